// Round 1
// baseline (3466.413 us; speedup 1.0000x reference)
//
#include <hip/hip_runtime.h>

#define NCH 128   // channels
#define NB  32    // nodes per GEMM block
#define KC  32    // k-chunk

// ---- degree histogram -------------------------------------------------------
__global__ __launch_bounds__(256) void k_deg(const int* __restrict__ dst,
                                             float* __restrict__ deg, int nE) {
  int e = blockIdx.x * 256 + threadIdx.x;
  if (e < nE) atomicAdd(&deg[dst[e]], 1.0f);
}

__global__ __launch_bounds__(256) void k_invdeg(float* __restrict__ deg, int n) {
  int i = blockIdx.x * 256 + threadIdx.x;
  if (i < n) deg[i] = 1.0f / fmaxf(deg[i], 1.0f);
}

// ---- edge-parallel scatter-sum: agg[dst] += x[src] --------------------------
// 32 lanes per edge, each lane handles 4 channels via float4 gather.
__global__ __launch_bounds__(256) void k_scatter(const float* __restrict__ x,
                                                 const int* __restrict__ src,
                                                 const int* __restrict__ dst,
                                                 float* __restrict__ agg, int nE) {
  int gid = blockIdx.x * 256 + threadIdx.x;
  int e = gid >> 5;
  if (e >= nE) return;
  int c = (gid & 31) << 2;
  int s = src[e];
  int d = dst[e];
  const float4 v = *reinterpret_cast<const float4*>(x + (size_t)s * NCH + c);
  float* p = agg + (size_t)d * NCH + c;
  atomicAdd(p + 0, v.x);
  atomicAdd(p + 1, v.y);
  atomicAdd(p + 2, v.z);
  atomicAdd(p + 3, v.w);
}

// ---- fused linear: out = [relu](aggsum*invdeg @ Wl^T + xin @ Wr^T + b) ------
// Block: 256 threads -> tile of NB=32 nodes x 128 cols. Weights + A staged in
// LDS (pad +1: Wl reads are 2-way aliased across wave64 = free; A reads are
// same-address broadcast).
__global__ __launch_bounds__(256) void k_linear(
    const float* __restrict__ aggsum, const float* __restrict__ xin,
    const float* __restrict__ invdeg, const float* __restrict__ Wl,
    const float* __restrict__ Wr, const float* __restrict__ bias,
    float* __restrict__ out, int relu, int nNodes) {
  __shared__ float sWl[NCH][KC + 1];
  __shared__ float sWr[NCH][KC + 1];
  __shared__ float sAa[NB][KC + 1];
  __shared__ float sAx[NB][KC + 1];

  int t = threadIdx.x;
  int node0 = blockIdx.x * NB;
  int o = t & (NCH - 1);   // output column 0..127
  int r0 = t >> 7;         // 0..1

  float acc[NB / 2];
#pragma unroll
  for (int i = 0; i < NB / 2; i++) acc[i] = 0.f;

  for (int kc = 0; kc < NCH; kc += KC) {
    __syncthreads();
    // W chunks: 128x32 each; consecutive threads load consecutive cols -> coalesced
    for (int i = t; i < NCH * KC; i += 256) {
      int row = i / KC, col = i % KC;
      sWl[row][col] = Wl[row * NCH + kc + col];
      sWr[row][col] = Wr[row * NCH + kc + col];
    }
    // A chunks: 32 nodes x 32 k, invdeg folded into agg load
    for (int i = t; i < NB * KC; i += 256) {
      int row = i / KC, col = i % KC;
      int n = node0 + row;
      if (n >= nNodes) n = nNodes - 1;  // clamp (value unused for invalid rows)
      float idg = invdeg[n];
      sAa[row][col] = aggsum[(size_t)n * NCH + kc + col] * idg;
      sAx[row][col] = xin[(size_t)n * NCH + kc + col];
    }
    __syncthreads();
#pragma unroll
    for (int i = 0; i < NB / 2; i++) {
      int r = r0 + 2 * i;
#pragma unroll
      for (int k = 0; k < KC; k++) {
        acc[i] += sAa[r][k] * sWl[o][k];
        acc[i] += sAx[r][k] * sWr[o][k];
      }
    }
  }

  float bv = bias[o];
#pragma unroll
  for (int i = 0; i < NB / 2; i++) {
    int n = node0 + r0 + 2 * i;
    if (n < nNodes) {
      float v = acc[i] + bv;
      if (relu) v = fmaxf(v, 0.f);
      out[(size_t)n * NCH + o] = v;
    }
  }
}

extern "C" void kernel_launch(void* const* d_in, const int* in_sizes, int n_in,
                              void* d_out, int out_size, void* d_ws, size_t ws_size,
                              hipStream_t stream) {
  const float* x   = (const float*)d_in[0];
  const int*   ei  = (const int*)d_in[1];
  const float* W1l = (const float*)d_in[2];
  const float* W1r = (const float*)d_in[3];
  const float* b1  = (const float*)d_in[4];
  const float* W2l = (const float*)d_in[5];
  const float* W2r = (const float*)d_in[6];
  const float* b2  = (const float*)d_in[7];
  float* out = (float*)d_out;

  const int nE = in_sizes[1] / 2;     // 800000
  const int nN = in_sizes[0] / NCH;   // 50000
  const int* src = ei;
  const int* dst = ei + nE;

  size_t featBytes = (size_t)nN * NCH * sizeof(float);  // 25.6 MB
  char* ws = (char*)d_ws;
  float* A   = (float*)ws;                    // agg sums (reused for layer 2)
  float* B   = (float*)(ws + featBytes);      // h (layer-1 output)
  float* deg = (float*)(ws + 2 * featBytes);  // deg -> invdeg, 50000 floats

  // ---- degrees (shared across both layers) ----
  hipMemsetAsync(deg, 0, (size_t)nN * sizeof(float), stream);
  k_deg<<<(nE + 255) / 256, 256, 0, stream>>>(dst, deg, nE);
  k_invdeg<<<(nN + 255) / 256, 256, 0, stream>>>(deg, nN);

  // ---- layer 1 ----
  hipMemsetAsync(A, 0, featBytes, stream);
  {
    long long threads = (long long)nE * 32;
    k_scatter<<<(unsigned)((threads + 255) / 256), 256, 0, stream>>>(x, src, dst, A, nE);
  }
  k_linear<<<(nN + NB - 1) / NB, 256, 0, stream>>>(A, x, deg, W1l, W1r, b1, B, 1, nN);

  // ---- layer 2 ----
  hipMemsetAsync(A, 0, featBytes, stream);
  {
    long long threads = (long long)nE * 32;
    k_scatter<<<(unsigned)((threads + 255) / 256), 256, 0, stream>>>(B, src, dst, A, nE);
  }
  k_linear<<<(nN + NB - 1) / NB, 256, 0, stream>>>(A, B, deg, W2l, W2r, b2, out, 0, nN);
}

// Round 2
// 1016.731 us; speedup vs baseline: 3.4094x; 3.4094x over previous
//
#include <hip/hip_runtime.h>

#define NCH 128   // channels
#define NB  32    // nodes per GEMM block
#define KC  32    // k-chunk

// ---- degree histogram (int) -------------------------------------------------
__global__ __launch_bounds__(256) void k_deg(const int* __restrict__ dst,
                                             int* __restrict__ deg, int nE) {
  int e = blockIdx.x * 256 + threadIdx.x;
  if (e < nE) atomicAdd(&deg[dst[e]], 1);
}

// ---- exclusive scan over degrees (single block), also emits 1/max(deg,1) ----
__global__ __launch_bounds__(1024) void k_scan(const int* __restrict__ deg,
                                               int* __restrict__ start,
                                               float* __restrict__ invdeg, int n) {
  __shared__ int sums[1024];
  int t = threadIdx.x;
  int per = (n + 1023) / 1024;
  int lo = t * per;
  int hi = lo + per; if (hi > n) hi = n;
  int s = 0;
  for (int i = lo; i < hi; i++) s += deg[i];
  sums[t] = s;
  __syncthreads();
  for (int off = 1; off < 1024; off <<= 1) {
    int v = 0;
    if (t >= off) v = sums[t - off];
    __syncthreads();
    if (t >= off) sums[t] += v;
    __syncthreads();
  }
  int run = (t == 0) ? 0 : sums[t - 1];
  for (int i = lo; i < hi; i++) {
    start[i] = run;
    int d = deg[i];
    invdeg[i] = 1.0f / fmaxf((float)d, 1.0f);
    run += d;
  }
  if (t == 1023) start[n] = run;  // == nE (threads past n contribute 0)
}

// ---- place edges into dst-sorted order (CSR) --------------------------------
__global__ __launch_bounds__(256) void k_place(const int* __restrict__ src,
                                               const int* __restrict__ dst,
                                               const int* __restrict__ start,
                                               int* __restrict__ cursor,
                                               int* __restrict__ srcSorted, int nE) {
  int e = blockIdx.x * 256 + threadIdx.x;
  if (e >= nE) return;
  int d = dst[e];
  int pos = start[d] + atomicAdd(&cursor[d], 1);
  srcSorted[pos] = src[e];
}

// ---- gather-mean: agg[n] = mean over CSR row of x[src] ----------------------
// 32 lanes per node, float4 per lane (512B per gathered row, coalesced).
__global__ __launch_bounds__(256) void k_gather(const float* __restrict__ x,
                                                const int* __restrict__ srcSorted,
                                                const int* __restrict__ start,
                                                const float* __restrict__ invdeg,
                                                float* __restrict__ agg, int nN) {
  int gid = blockIdx.x * 256 + threadIdx.x;
  int node = gid >> 5;
  if (node >= nN) return;
  int c = (gid & 31) << 2;
  int s0 = start[node], s1 = start[node + 1];
  float ax = 0.f, ay = 0.f, az = 0.f, aw = 0.f;
  for (int i = s0; i < s1; i++) {
    int s = srcSorted[i];
    const float4 v = *reinterpret_cast<const float4*>(x + (size_t)s * NCH + c);
    ax += v.x; ay += v.y; az += v.z; aw += v.w;
  }
  float idg = invdeg[node];
  float4 o = make_float4(ax * idg, ay * idg, az * idg, aw * idg);
  *reinterpret_cast<float4*>(agg + (size_t)node * NCH + c) = o;
}

// ---- fused linear: out = [relu](agg @ Wl^T + xin @ Wr^T + b) ----------------
__global__ __launch_bounds__(256) void k_linear(
    const float* __restrict__ agg, const float* __restrict__ xin,
    const float* __restrict__ Wl, const float* __restrict__ Wr,
    const float* __restrict__ bias, float* __restrict__ out, int relu, int nNodes) {
  __shared__ float sWl[NCH][KC + 1];
  __shared__ float sWr[NCH][KC + 1];
  __shared__ float sAa[NB][KC + 1];
  __shared__ float sAx[NB][KC + 1];

  int t = threadIdx.x;
  int node0 = blockIdx.x * NB;
  int o = t & (NCH - 1);
  int r0 = t >> 7;

  float acc[NB / 2];
#pragma unroll
  for (int i = 0; i < NB / 2; i++) acc[i] = 0.f;

  for (int kc = 0; kc < NCH; kc += KC) {
    __syncthreads();
    for (int i = t; i < NCH * KC; i += 256) {
      int row = i / KC, col = i % KC;
      sWl[row][col] = Wl[row * NCH + kc + col];
      sWr[row][col] = Wr[row * NCH + kc + col];
    }
    for (int i = t; i < NB * KC; i += 256) {
      int row = i / KC, col = i % KC;
      int n = node0 + row;
      if (n >= nNodes) n = nNodes - 1;
      sAa[row][col] = agg[(size_t)n * NCH + kc + col];
      sAx[row][col] = xin[(size_t)n * NCH + kc + col];
    }
    __syncthreads();
#pragma unroll
    for (int i = 0; i < NB / 2; i++) {
      int r = r0 + 2 * i;
#pragma unroll
      for (int k = 0; k < KC; k++) {
        acc[i] += sAa[r][k] * sWl[o][k];
        acc[i] += sAx[r][k] * sWr[o][k];
      }
    }
  }

  float bv = bias[o];
#pragma unroll
  for (int i = 0; i < NB / 2; i++) {
    int n = node0 + r0 + 2 * i;
    if (n < nNodes) {
      float v = acc[i] + bv;
      if (relu) v = fmaxf(v, 0.f);
      out[(size_t)n * NCH + o] = v;
    }
  }
}

extern "C" void kernel_launch(void* const* d_in, const int* in_sizes, int n_in,
                              void* d_out, int out_size, void* d_ws, size_t ws_size,
                              hipStream_t stream) {
  const float* x   = (const float*)d_in[0];
  const int*   ei  = (const int*)d_in[1];
  const float* W1l = (const float*)d_in[2];
  const float* W1r = (const float*)d_in[3];
  const float* b1  = (const float*)d_in[4];
  const float* W2l = (const float*)d_in[5];
  const float* W2r = (const float*)d_in[6];
  const float* b2  = (const float*)d_in[7];
  float* out = (float*)d_out;

  const int nE = in_sizes[1] / 2;     // 800000
  const int nN = in_sizes[0] / NCH;   // 50000
  const int* src = ei;
  const int* dst = ei + nE;

  size_t featBytes = (size_t)nN * NCH * sizeof(float);  // 25.6 MB
  size_t nodeInts  = (size_t)(nN + 1) * sizeof(int);

  char* ws = (char*)d_ws;
  float* A         = (float*)ws;                         ws += featBytes;
  float* B         = (float*)ws;                         ws += featBytes;
  int*   deg       = (int*)ws;                           ws += nodeInts;
  int*   startRow  = (int*)ws;                           ws += nodeInts;
  int*   cursor    = (int*)ws;                           ws += nodeInts;
  float* invdeg    = (float*)ws;                         ws += nodeInts;
  int*   srcSorted = (int*)ws;

  // ---- CSR build (per call; deterministic work) ----
  hipMemsetAsync(deg, 0, (size_t)nN * sizeof(int), stream);
  hipMemsetAsync(cursor, 0, (size_t)nN * sizeof(int), stream);
  k_deg<<<(nE + 255) / 256, 256, 0, stream>>>(dst, deg, nE);
  k_scan<<<1, 1024, 0, stream>>>(deg, startRow, invdeg, nN);
  k_place<<<(nE + 255) / 256, 256, 0, stream>>>(src, dst, startRow, cursor, srcSorted, nE);

  int gatherBlocks = (nN * 32 + 255) / 256;

  // ---- layer 1 ----
  k_gather<<<gatherBlocks, 256, 0, stream>>>(x, srcSorted, startRow, invdeg, A, nN);
  k_linear<<<(nN + NB - 1) / NB, 256, 0, stream>>>(A, x, W1l, W1r, b1, B, 1, nN);

  // ---- layer 2 ----
  k_gather<<<gatherBlocks, 256, 0, stream>>>(B, srcSorted, startRow, invdeg, A, nN);
  k_linear<<<(nN + NB - 1) / NB, 256, 0, stream>>>(A, B, W2l, W2r, b2, out, 0, nN);
}

// Round 3
// 475.268 us; speedup vs baseline: 7.2936x; 2.1393x over previous
//
#include <hip/hip_runtime.h>

#define NCH 128

typedef __attribute__((ext_vector_type(8))) short bf16x8;
typedef __attribute__((ext_vector_type(4))) float f32x4;

// ---- degree histogram (int) -------------------------------------------------
__global__ __launch_bounds__(256) void k_deg(const int* __restrict__ dst,
                                             int* __restrict__ deg, int nE) {
  int e = blockIdx.x * 256 + threadIdx.x;
  if (e < nE) atomicAdd(&deg[dst[e]], 1);
}

// ---- exclusive scan over degrees (single block), also emits 1/max(deg,1) ----
__global__ __launch_bounds__(1024) void k_scan(const int* __restrict__ deg,
                                               int* __restrict__ start,
                                               float* __restrict__ invdeg, int n) {
  __shared__ int sums[1024];
  int t = threadIdx.x;
  int per = (n + 1023) / 1024;
  int lo = t * per;
  int hi = lo + per; if (hi > n) hi = n;
  int s = 0;
  for (int i = lo; i < hi; i++) s += deg[i];
  sums[t] = s;
  __syncthreads();
  for (int off = 1; off < 1024; off <<= 1) {
    int v = 0;
    if (t >= off) v = sums[t - off];
    __syncthreads();
    if (t >= off) sums[t] += v;
    __syncthreads();
  }
  int run = (t == 0) ? 0 : sums[t - 1];
  for (int i = lo; i < hi; i++) {
    start[i] = run;
    int d = deg[i];
    invdeg[i] = 1.0f / fmaxf((float)d, 1.0f);
    run += d;
  }
  if (t == 1023) start[n] = run;
}

// ---- place edges into dst-sorted order (CSR) --------------------------------
__global__ __launch_bounds__(256) void k_place(const int* __restrict__ src,
                                               const int* __restrict__ dst,
                                               const int* __restrict__ start,
                                               int* __restrict__ cursor,
                                               int* __restrict__ srcSorted, int nE) {
  int e = blockIdx.x * 256 + threadIdx.x;
  if (e >= nE) return;
  int d = dst[e];
  int pos = start[d] + atomicAdd(&cursor[d], 1);
  srcSorted[pos] = src[e];
}

// ---- gather-mean: agg[n] = mean over CSR row of x[src] ----------------------
__global__ __launch_bounds__(256) void k_gather(const float* __restrict__ x,
                                                const int* __restrict__ srcSorted,
                                                const int* __restrict__ start,
                                                const float* __restrict__ invdeg,
                                                float* __restrict__ agg, int nN) {
  int gid = blockIdx.x * 256 + threadIdx.x;
  int node = gid >> 5;
  if (node >= nN) return;
  int c = (gid & 31) << 2;
  int s0 = start[node], s1 = start[node + 1];
  float ax = 0.f, ay = 0.f, az = 0.f, aw = 0.f;
  for (int i = s0; i < s1; i++) {
    int s = srcSorted[i];
    const float4 v = *reinterpret_cast<const float4*>(x + (size_t)s * NCH + c);
    ax += v.x; ay += v.y; az += v.z; aw += v.w;
  }
  float idg = invdeg[node];
  float4 o = make_float4(ax * idg, ay * idg, az * idg, aw * idg);
  *reinterpret_cast<float4*>(agg + (size_t)node * NCH + c) = o;
}

// ---- prep: Wcat[j][k] (k<128 -> Wl[j][k], else Wr[j][k-128]) split to bf16 hi/lo
__global__ __launch_bounds__(256) void k_prepW(const float* __restrict__ Wl,
                                               const float* __restrict__ Wr,
                                               unsigned short* __restrict__ Whi,
                                               unsigned short* __restrict__ Wlo) {
  int i = blockIdx.x * 256 + threadIdx.x;  // 128*256
  if (i >= 128 * 256) return;
  int j = i >> 8, k = i & 255;
  float w = (k < 128) ? Wl[j * 128 + k] : Wr[j * 128 + (k - 128)];
  unsigned u = __float_as_uint(w);
  float fhi = __uint_as_float(u & 0xFFFF0000u);
  float flo = w - fhi;
  Whi[i] = (unsigned short)(u >> 16);
  Wlo[i] = (unsigned short)(__float_as_uint(flo) >> 16);
}

// ---- MFMA linear: out = [relu]( [agg|x] @ Wcat + b ) ------------------------
// 4 waves/block, wave = 16 rows x 128 cols. K=256 in 8 chunks of 32.
// Split-bf16: a*b ~= ahi*bhi + ahi*blo + alo*bhi  (error ~3e-4 abs).
// A-frag: row=lane&15, k=(lane>>4)*8+i (direct global, coalesced per-row 128B).
// B-frag: col=lane&15, same k (16B loads from L1/L2-resident Whi/Wlo).
__global__ __launch_bounds__(256) void k_linear_mfma(
    const float* __restrict__ agg, const float* __restrict__ xin,
    const unsigned short* __restrict__ Whi, const unsigned short* __restrict__ Wlo,
    const float* __restrict__ bias, float* __restrict__ out,
    int relu, int nNodes) {
  int t = threadIdx.x;
  int wave = t >> 6;
  int lane = t & 63;
  int l15 = lane & 15;
  int lq  = lane >> 4;                       // 0..3
  int r0 = (blockIdx.x * 4 + wave) * 16;     // wave's first row

  f32x4 acc[8];
#pragma unroll
  for (int i = 0; i < 8; i++) acc[i] = (f32x4){0.f, 0.f, 0.f, 0.f};

  int arow = r0 + l15;
  if (arow >= nNodes) arow = nNodes - 1;     // clamp; masked at write

#pragma unroll
  for (int kc = 0; kc < 8; kc++) {
    const float* abase = (kc < 4) ? agg : xin;
    int k128 = (kc & 3) * 32 + lq * 8;       // k within the 128-wide half
    const float* ap = abase + (size_t)arow * NCH + k128;
    float4 v0 = *reinterpret_cast<const float4*>(ap);
    float4 v1 = *reinterpret_cast<const float4*>(ap + 4);
    float av[8] = {v0.x, v0.y, v0.z, v0.w, v1.x, v1.y, v1.z, v1.w};
    bf16x8 ahi, alo;
#pragma unroll
    for (int i = 0; i < 8; i++) {
      unsigned u = __float_as_uint(av[i]);
      float fhi = __uint_as_float(u & 0xFFFF0000u);
      float flo = av[i] - fhi;
      ahi[i] = (short)(u >> 16);
      alo[i] = (short)(__float_as_uint(flo) >> 16);
    }
    int kglob = kc * 32 + lq * 8;            // k within 256
#pragma unroll
    for (int nt = 0; nt < 8; nt++) {
      int j = nt * 16 + l15;
      bf16x8 bhi = *reinterpret_cast<const bf16x8*>(Whi + j * 256 + kglob);
      bf16x8 blo = *reinterpret_cast<const bf16x8*>(Wlo + j * 256 + kglob);
      acc[nt] = __builtin_amdgcn_mfma_f32_16x16x32_bf16(ahi, bhi, acc[nt], 0, 0, 0);
      acc[nt] = __builtin_amdgcn_mfma_f32_16x16x32_bf16(ahi, blo, acc[nt], 0, 0, 0);
      acc[nt] = __builtin_amdgcn_mfma_f32_16x16x32_bf16(alo, bhi, acc[nt], 0, 0, 0);
    }
  }

#pragma unroll
  for (int nt = 0; nt < 8; nt++) {
    int col = nt * 16 + l15;
    float bv = bias[col];
#pragma unroll
    for (int i = 0; i < 4; i++) {
      int row = r0 + lq * 4 + i;
      if (row < nNodes) {
        float v = acc[nt][i] + bv;
        if (relu) v = fmaxf(v, 0.f);
        out[(size_t)row * NCH + col] = v;
      }
    }
  }
}

extern "C" void kernel_launch(void* const* d_in, const int* in_sizes, int n_in,
                              void* d_out, int out_size, void* d_ws, size_t ws_size,
                              hipStream_t stream) {
  const float* x   = (const float*)d_in[0];
  const int*   ei  = (const int*)d_in[1];
  const float* W1l = (const float*)d_in[2];
  const float* W1r = (const float*)d_in[3];
  const float* b1  = (const float*)d_in[4];
  const float* W2l = (const float*)d_in[5];
  const float* W2r = (const float*)d_in[6];
  const float* b2  = (const float*)d_in[7];
  float* out = (float*)d_out;

  const int nE = in_sizes[1] / 2;     // 800000
  const int nN = in_sizes[0] / NCH;   // 50000
  const int* src = ei;
  const int* dst = ei + nE;

  size_t featBytes = (size_t)nN * NCH * sizeof(float);   // 25.6 MB
  size_t nodeInts  = (size_t)(nN + 1) * sizeof(int);
  size_t wBytes    = (size_t)128 * 256 * sizeof(unsigned short);  // 64 KB

  char* ws = (char*)d_ws;
  float* A         = (float*)ws;                         ws += featBytes;
  float* B         = (float*)ws;                         ws += featBytes;
  int*   deg       = (int*)ws;                           ws += nodeInts;
  int*   startRow  = (int*)ws;                           ws += nodeInts;
  int*   cursor    = (int*)ws;                           ws += nodeInts;
  float* invdeg    = (float*)ws;                         ws += nodeInts;
  int*   srcSorted = (int*)ws;                           ws += (size_t)nE * sizeof(int);
  unsigned short* W1hi = (unsigned short*)ws;            ws += wBytes;
  unsigned short* W1lo = (unsigned short*)ws;            ws += wBytes;
  unsigned short* W2hi = (unsigned short*)ws;            ws += wBytes;
  unsigned short* W2lo = (unsigned short*)ws;            ws += wBytes;

  // ---- CSR build + weight prep ----
  hipMemsetAsync(deg, 0, (size_t)nN * sizeof(int), stream);
  hipMemsetAsync(cursor, 0, (size_t)nN * sizeof(int), stream);
  k_deg<<<(nE + 255) / 256, 256, 0, stream>>>(dst, deg, nE);
  k_scan<<<1, 1024, 0, stream>>>(deg, startRow, invdeg, nN);
  k_place<<<(nE + 255) / 256, 256, 0, stream>>>(src, dst, startRow, cursor, srcSorted, nE);
  k_prepW<<<(128 * 256 + 255) / 256, 256, 0, stream>>>(W1l, W1r, W1hi, W1lo);
  k_prepW<<<(128 * 256 + 255) / 256, 256, 0, stream>>>(W2l, W2r, W2hi, W2lo);

  int gatherBlocks = (nN * 32 + 255) / 256;
  int linBlocks = (nN + 63) / 64;

  // ---- layer 1 ----
  k_gather<<<gatherBlocks, 256, 0, stream>>>(x, srcSorted, startRow, invdeg, A, nN);
  k_linear_mfma<<<linBlocks, 256, 0, stream>>>(A, x, W1hi, W1lo, b1, B, 1, nN);

  // ---- layer 2 ----
  k_gather<<<gatherBlocks, 256, 0, stream>>>(B, srcSorted, startRow, invdeg, A, nN);
  k_linear_mfma<<<linBlocks, 256, 0, stream>>>(A, B, W2hi, W2lo, b2, out, 0, nN);
}

// Round 4
// 360.249 us; speedup vs baseline: 9.6223x; 1.3193x over previous
//
#include <hip/hip_runtime.h>

#define NCH 128
#define SCAN_CHUNK 1024

typedef __attribute__((ext_vector_type(8))) short bf16x8;
typedef __attribute__((ext_vector_type(4))) float f32x4;

// ---- degree histogram (int) -------------------------------------------------
__global__ __launch_bounds__(256) void k_deg(const int* __restrict__ dst,
                                             int* __restrict__ deg, int nE) {
  int e = blockIdx.x * 256 + threadIdx.x;
  if (e < nE) atomicAdd(&deg[dst[e]], 1);
}

// ---- hierarchical scan, phase 1: per-1024-chunk sums ------------------------
__global__ __launch_bounds__(256) void k_chunksum(const int* __restrict__ deg,
                                                  int* __restrict__ chunkSum, int nN) {
  int t = threadIdx.x;
  int base = blockIdx.x * SCAN_CHUNK + t * 4;
  int s = 0;
  if (base < nN) {  // nN % 4 == 0 -> full int4 or nothing
    int4 d = *reinterpret_cast<const int4*>(deg + base);
    s = d.x + d.y + d.z + d.w;
  }
  for (int off = 32; off; off >>= 1) s += __shfl_down(s, off);
  __shared__ int red[4];
  if ((t & 63) == 0) red[t >> 6] = s;
  __syncthreads();
  if (t == 0) chunkSum[blockIdx.x] = red[0] + red[1] + red[2] + red[3];
}

// ---- hierarchical scan, phase 2: per-chunk exclusive scan + offset ----------
// Each block recomputes its chunk offset from chunkSum (<=64 chunks, wave-reduce).
__global__ __launch_bounds__(256) void k_finalize(const int* __restrict__ deg,
                                                  const int* __restrict__ chunkSum,
                                                  int* __restrict__ start,
                                                  float* __restrict__ invdeg, int nN) {
  int b = blockIdx.x, t = threadIdx.x;
  int base = b * SCAN_CHUNK + t * 4;

  __shared__ int s_coff;
  if (t < 64) {
    int v = (t < b) ? chunkSum[t] : 0;
    for (int off = 32; off; off >>= 1) v += __shfl_down(v, off);
    if (t == 0) s_coff = v;
  }

  int4 d = make_int4(0, 0, 0, 0);
  if (base < nN) d = *reinterpret_cast<const int4*>(deg + base);
  int s = d.x + d.y + d.z + d.w;

  __shared__ int ts[256];
  ts[t] = s;
  __syncthreads();
  for (int off = 1; off < 256; off <<= 1) {
    int v = (t >= off) ? ts[t - off] : 0;
    __syncthreads();
    ts[t] += v;
    __syncthreads();
  }

  if (base < nN) {
    int run = s_coff + ts[t] - s;  // exclusive prefix for element base
    int dv[4] = {d.x, d.y, d.z, d.w};
#pragma unroll
    for (int j = 0; j < 4; j++) {
      start[base + j] = run;
      invdeg[base + j] = 1.0f / fmaxf((float)dv[j], 1.0f);
      run += dv[j];
    }
  }
  if (b == gridDim.x - 1 && t == 255) start[nN] = s_coff + ts[255];
}

// ---- place edges into dst-sorted order (CSR) --------------------------------
__global__ __launch_bounds__(256) void k_place(const int* __restrict__ src,
                                               const int* __restrict__ dst,
                                               const int* __restrict__ start,
                                               int* __restrict__ cursor,
                                               int* __restrict__ srcSorted, int nE) {
  int e = blockIdx.x * 256 + threadIdx.x;
  if (e >= nE) return;
  int d = dst[e];
  int pos = start[d] + atomicAdd(&cursor[d], 1);
  srcSorted[pos] = src[e];
}

// ---- gather-mean: agg[n] = mean over CSR row of x[src], unroll x4 -----------
__global__ __launch_bounds__(256) void k_gather(const float* __restrict__ x,
                                                const int* __restrict__ srcSorted,
                                                const int* __restrict__ start,
                                                const float* __restrict__ invdeg,
                                                float* __restrict__ agg, int nN) {
  int gid = blockIdx.x * 256 + threadIdx.x;
  int node = gid >> 5;
  if (node >= nN) return;
  int c = (gid & 31) << 2;
  int s0 = start[node], s1 = start[node + 1];
  float ax = 0.f, ay = 0.f, az = 0.f, aw = 0.f;
  int i = s0;
  for (; i + 4 <= s1; i += 4) {
    int sa = srcSorted[i], sb = srcSorted[i + 1];
    int sc = srcSorted[i + 2], sd = srcSorted[i + 3];
    float4 va = *reinterpret_cast<const float4*>(x + (size_t)sa * NCH + c);
    float4 vb = *reinterpret_cast<const float4*>(x + (size_t)sb * NCH + c);
    float4 vc = *reinterpret_cast<const float4*>(x + (size_t)sc * NCH + c);
    float4 vd = *reinterpret_cast<const float4*>(x + (size_t)sd * NCH + c);
    ax += va.x + vb.x + vc.x + vd.x;
    ay += va.y + vb.y + vc.y + vd.y;
    az += va.z + vb.z + vc.z + vd.z;
    aw += va.w + vb.w + vc.w + vd.w;
  }
  for (; i < s1; i++) {
    int s = srcSorted[i];
    const float4 v = *reinterpret_cast<const float4*>(x + (size_t)s * NCH + c);
    ax += v.x; ay += v.y; az += v.z; aw += v.w;
  }
  float idg = invdeg[node];
  float4 o = make_float4(ax * idg, ay * idg, az * idg, aw * idg);
  *reinterpret_cast<float4*>(agg + (size_t)node * NCH + c) = o;
}

// ---- prep: Wcat[j][k] (k<128 -> Wl[j][k], else Wr[j][k-128]) split to bf16 hi/lo
__global__ __launch_bounds__(256) void k_prepW(const float* __restrict__ Wl,
                                               const float* __restrict__ Wr,
                                               unsigned short* __restrict__ Whi,
                                               unsigned short* __restrict__ Wlo) {
  int i = blockIdx.x * 256 + threadIdx.x;  // 128*256
  if (i >= 128 * 256) return;
  int j = i >> 8, k = i & 255;
  float w = (k < 128) ? Wl[j * 128 + k] : Wr[j * 128 + (k - 128)];
  unsigned u = __float_as_uint(w);
  float fhi = __uint_as_float(u & 0xFFFF0000u);
  float flo = w - fhi;
  Whi[i] = (unsigned short)(u >> 16);
  Wlo[i] = (unsigned short)(__float_as_uint(flo) >> 16);
}

// ---- MFMA linear: out = [relu]( [agg|x] @ Wcat + b ) ------------------------
__global__ __launch_bounds__(256) void k_linear_mfma(
    const float* __restrict__ agg, const float* __restrict__ xin,
    const unsigned short* __restrict__ Whi, const unsigned short* __restrict__ Wlo,
    const float* __restrict__ bias, float* __restrict__ out,
    int relu, int nNodes) {
  int t = threadIdx.x;
  int wave = t >> 6;
  int lane = t & 63;
  int l15 = lane & 15;
  int lq  = lane >> 4;                       // 0..3
  int r0 = (blockIdx.x * 4 + wave) * 16;     // wave's first row

  f32x4 acc[8];
#pragma unroll
  for (int i = 0; i < 8; i++) acc[i] = (f32x4){0.f, 0.f, 0.f, 0.f};

  int arow = r0 + l15;
  if (arow >= nNodes) arow = nNodes - 1;     // clamp; masked at write

#pragma unroll
  for (int kc = 0; kc < 8; kc++) {
    const float* abase = (kc < 4) ? agg : xin;
    int k128 = (kc & 3) * 32 + lq * 8;
    const float* ap = abase + (size_t)arow * NCH + k128;
    float4 v0 = *reinterpret_cast<const float4*>(ap);
    float4 v1 = *reinterpret_cast<const float4*>(ap + 4);
    float av[8] = {v0.x, v0.y, v0.z, v0.w, v1.x, v1.y, v1.z, v1.w};
    bf16x8 ahi, alo;
#pragma unroll
    for (int i = 0; i < 8; i++) {
      unsigned u = __float_as_uint(av[i]);
      float fhi = __uint_as_float(u & 0xFFFF0000u);
      float flo = av[i] - fhi;
      ahi[i] = (short)(u >> 16);
      alo[i] = (short)(__float_as_uint(flo) >> 16);
    }
    int kglob = kc * 32 + lq * 8;
#pragma unroll
    for (int nt = 0; nt < 8; nt++) {
      int j = nt * 16 + l15;
      bf16x8 bhi = *reinterpret_cast<const bf16x8*>(Whi + j * 256 + kglob);
      bf16x8 blo = *reinterpret_cast<const bf16x8*>(Wlo + j * 256 + kglob);
      acc[nt] = __builtin_amdgcn_mfma_f32_16x16x32_bf16(ahi, bhi, acc[nt], 0, 0, 0);
      acc[nt] = __builtin_amdgcn_mfma_f32_16x16x32_bf16(ahi, blo, acc[nt], 0, 0, 0);
      acc[nt] = __builtin_amdgcn_mfma_f32_16x16x32_bf16(alo, bhi, acc[nt], 0, 0, 0);
    }
  }

#pragma unroll
  for (int nt = 0; nt < 8; nt++) {
    int col = nt * 16 + l15;
    float bv = bias[col];
#pragma unroll
    for (int i = 0; i < 4; i++) {
      int row = r0 + lq * 4 + i;
      if (row < nNodes) {
        float v = acc[nt][i] + bv;
        if (relu) v = fmaxf(v, 0.f);
        out[(size_t)row * NCH + col] = v;
      }
    }
  }
}

extern "C" void kernel_launch(void* const* d_in, const int* in_sizes, int n_in,
                              void* d_out, int out_size, void* d_ws, size_t ws_size,
                              hipStream_t stream) {
  const float* x   = (const float*)d_in[0];
  const int*   ei  = (const int*)d_in[1];
  const float* W1l = (const float*)d_in[2];
  const float* W1r = (const float*)d_in[3];
  const float* b1  = (const float*)d_in[4];
  const float* W2l = (const float*)d_in[5];
  const float* W2r = (const float*)d_in[6];
  const float* b2  = (const float*)d_in[7];
  float* out = (float*)d_out;

  const int nE = in_sizes[1] / 2;     // 800000
  const int nN = in_sizes[0] / NCH;   // 50000
  const int* src = ei;
  const int* dst = ei + nE;

  size_t featBytes = (size_t)nN * NCH * sizeof(float);   // 25.6 MB
  size_t nodeInts  = (size_t)(nN + 1) * sizeof(int);
  size_t wBytes    = (size_t)128 * 256 * sizeof(unsigned short);  // 64 KB
  const int nChunks = (nN + SCAN_CHUNK - 1) / SCAN_CHUNK;         // 49

  char* ws = (char*)d_ws;
  float* A         = (float*)ws;                         ws += featBytes;
  float* B         = (float*)ws;                         ws += featBytes;
  int*   deg       = (int*)ws;                           ws += nodeInts;
  int*   startRow  = (int*)ws;                           ws += nodeInts;
  int*   cursor    = (int*)ws;                           ws += nodeInts;
  float* invdeg    = (float*)ws;                         ws += nodeInts;
  int*   srcSorted = (int*)ws;                           ws += (size_t)nE * sizeof(int);
  unsigned short* W1hi = (unsigned short*)ws;            ws += wBytes;
  unsigned short* W1lo = (unsigned short*)ws;            ws += wBytes;
  unsigned short* W2hi = (unsigned short*)ws;            ws += wBytes;
  unsigned short* W2lo = (unsigned short*)ws;            ws += wBytes;
  int*   chunkSum  = (int*)ws;                           ws += (size_t)nChunks * sizeof(int);

  // ---- CSR build + weight prep ----
  hipMemsetAsync(deg, 0, (size_t)nN * sizeof(int), stream);
  hipMemsetAsync(cursor, 0, (size_t)nN * sizeof(int), stream);
  k_deg<<<(nE + 255) / 256, 256, 0, stream>>>(dst, deg, nE);
  k_chunksum<<<nChunks, 256, 0, stream>>>(deg, chunkSum, nN);
  k_finalize<<<nChunks, 256, 0, stream>>>(deg, chunkSum, startRow, invdeg, nN);
  k_place<<<(nE + 255) / 256, 256, 0, stream>>>(src, dst, startRow, cursor, srcSorted, nE);
  k_prepW<<<(128 * 256 + 255) / 256, 256, 0, stream>>>(W1l, W1r, W1hi, W1lo);
  k_prepW<<<(128 * 256 + 255) / 256, 256, 0, stream>>>(W2l, W2r, W2hi, W2lo);

  int gatherBlocks = (nN * 32 + 255) / 256;
  int linBlocks = (nN + 63) / 64;

  // ---- layer 1 ----
  k_gather<<<gatherBlocks, 256, 0, stream>>>(x, srcSorted, startRow, invdeg, A, nN);
  k_linear_mfma<<<linBlocks, 256, 0, stream>>>(A, x, W1hi, W1lo, b1, B, 1, nN);

  // ---- layer 2 ----
  k_gather<<<gatherBlocks, 256, 0, stream>>>(B, srcSorted, startRow, invdeg, A, nN);
  k_linear_mfma<<<linBlocks, 256, 0, stream>>>(A, B, W2hi, W2lo, b2, out, 0, nN);
}

// Round 5
// 268.558 us; speedup vs baseline: 12.9075x; 1.3414x over previous
//
#include <hip/hip_runtime.h>

#define NCH 128
#define SCAN_CHUNK 1024

typedef __attribute__((ext_vector_type(8))) short bf16x8;
typedef __attribute__((ext_vector_type(4))) float f32x4;

// ---- degree histogram (int) -------------------------------------------------
__global__ __launch_bounds__(256) void k_deg(const int* __restrict__ dst,
                                             int* __restrict__ deg, int nE) {
  int e = blockIdx.x * 256 + threadIdx.x;
  if (e < nE) atomicAdd(&deg[dst[e]], 1);
}

// ---- hierarchical scan, phase 1: per-1024-chunk sums ------------------------
__global__ __launch_bounds__(256) void k_chunksum(const int* __restrict__ deg,
                                                  int* __restrict__ chunkSum, int nN) {
  int t = threadIdx.x;
  int base = blockIdx.x * SCAN_CHUNK + t * 4;
  int s = 0;
  if (base < nN) {
    int4 d = *reinterpret_cast<const int4*>(deg + base);
    s = d.x + d.y + d.z + d.w;
  }
  for (int off = 32; off; off >>= 1) s += __shfl_down(s, off);
  __shared__ int red[4];
  if ((t & 63) == 0) red[t >> 6] = s;
  __syncthreads();
  if (t == 0) chunkSum[blockIdx.x] = red[0] + red[1] + red[2] + red[3];
}

// ---- hierarchical scan, phase 2: per-chunk exclusive scan + offset ----------
__global__ __launch_bounds__(256) void k_finalize(const int* __restrict__ deg,
                                                  const int* __restrict__ chunkSum,
                                                  int* __restrict__ start,
                                                  float* __restrict__ invdeg, int nN) {
  int b = blockIdx.x, t = threadIdx.x;
  int base = b * SCAN_CHUNK + t * 4;

  __shared__ int s_coff;
  if (t < 64) {
    int v = (t < b) ? chunkSum[t] : 0;
    for (int off = 32; off; off >>= 1) v += __shfl_down(v, off);
    if (t == 0) s_coff = v;
  }

  int4 d = make_int4(0, 0, 0, 0);
  if (base < nN) d = *reinterpret_cast<const int4*>(deg + base);
  int s = d.x + d.y + d.z + d.w;

  __shared__ int ts[256];
  ts[t] = s;
  __syncthreads();
  for (int off = 1; off < 256; off <<= 1) {
    int v = (t >= off) ? ts[t - off] : 0;
    __syncthreads();
    ts[t] += v;
    __syncthreads();
  }

  if (base < nN) {
    int run = s_coff + ts[t] - s;
    int dv[4] = {d.x, d.y, d.z, d.w};
#pragma unroll
    for (int j = 0; j < 4; j++) {
      start[base + j] = run;
      invdeg[base + j] = 1.0f / fmaxf((float)dv[j], 1.0f);
      run += dv[j];
    }
  }
  if (b == gridDim.x - 1 && t == 255) start[nN] = s_coff + ts[255];
}

// ---- place edges into dst-sorted order (CSR) --------------------------------
__global__ __launch_bounds__(256) void k_place(const int* __restrict__ src,
                                               const int* __restrict__ dst,
                                               const int* __restrict__ start,
                                               int* __restrict__ cursor,
                                               int* __restrict__ srcSorted, int nE) {
  int e = blockIdx.x * 256 + threadIdx.x;
  if (e >= nE) return;
  int d = dst[e];
  int pos = start[d] + atomicAdd(&cursor[d], 1);
  srcSorted[pos] = src[e];
}

// ---- gather-mean: agg[n] = mean over CSR row of x[src], unroll x4 -----------
__global__ __launch_bounds__(256) void k_gather(const float* __restrict__ x,
                                                const int* __restrict__ srcSorted,
                                                const int* __restrict__ start,
                                                const float* __restrict__ invdeg,
                                                float* __restrict__ agg, int nN) {
  int gid = blockIdx.x * 256 + threadIdx.x;
  int node = gid >> 5;
  if (node >= nN) return;
  int c = (gid & 31) << 2;
  int s0 = start[node], s1 = start[node + 1];
  float ax = 0.f, ay = 0.f, az = 0.f, aw = 0.f;
  int i = s0;
  for (; i + 4 <= s1; i += 4) {
    int sa = srcSorted[i], sb = srcSorted[i + 1];
    int sc = srcSorted[i + 2], sd = srcSorted[i + 3];
    float4 va = *reinterpret_cast<const float4*>(x + (size_t)sa * NCH + c);
    float4 vb = *reinterpret_cast<const float4*>(x + (size_t)sb * NCH + c);
    float4 vc = *reinterpret_cast<const float4*>(x + (size_t)sc * NCH + c);
    float4 vd = *reinterpret_cast<const float4*>(x + (size_t)sd * NCH + c);
    ax += va.x + vb.x + vc.x + vd.x;
    ay += va.y + vb.y + vc.y + vd.y;
    az += va.z + vb.z + vc.z + vd.z;
    aw += va.w + vb.w + vc.w + vd.w;
  }
  for (; i < s1; i++) {
    int s = srcSorted[i];
    const float4 v = *reinterpret_cast<const float4*>(x + (size_t)s * NCH + c);
    ax += v.x; ay += v.y; az += v.z; aw += v.w;
  }
  float idg = invdeg[node];
  float4 o = make_float4(ax * idg, ay * idg, az * idg, aw * idg);
  *reinterpret_cast<float4*>(agg + (size_t)node * NCH + c) = o;
}

// ---- prep: fragment-ordered split-bf16 weights ------------------------------
// Wf index = ((kc*8 + nt)*64 + lane)*8 + e, holding Wcat[j][k] with
// j = nt*16 + (lane&15), k = kc*32 + (lane>>4)*8 + e.
// A wave's B-fragment load for (kc,nt) is then base + (kc*8+nt)*1024 + lane*16:
// one fully-coalesced 1KB read, sequential across the inner loops.
__global__ __launch_bounds__(256) void k_prepW(const float* __restrict__ Wl,
                                               const float* __restrict__ Wr,
                                               unsigned short* __restrict__ WhiF,
                                               unsigned short* __restrict__ WloF) {
  int i = blockIdx.x * 256 + threadIdx.x;  // 32768 elements
  if (i >= 32768) return;
  int kc   = i >> 12;
  int r    = i & 4095;
  int nt   = r >> 9;
  int r2   = r & 511;
  int lane = r2 >> 3;
  int e    = r2 & 7;
  int j = nt * 16 + (lane & 15);
  int k = kc * 32 + (lane >> 4) * 8 + e;
  float w = (k < 128) ? Wl[j * 128 + k] : Wr[j * 128 + (k - 128)];
  unsigned u = __float_as_uint(w);
  float fhi = __uint_as_float(u & 0xFFFF0000u);
  float flo = w - fhi;
  WhiF[i] = (unsigned short)(u >> 16);
  WloF[i] = (unsigned short)(__float_as_uint(flo) >> 16);
}

// ---- MFMA linear: out = [relu]( [agg|x] @ Wcat + b ) ------------------------
// launch_bounds(256,4): cap VGPR at 128 so the compiler can keep ~12 B-loads
// in flight (R4 post-mortem: VGPR=68 gave MLP~2, latency-serialized L2 reads).
__global__ __launch_bounds__(256, 4) void k_linear_mfma(
    const float* __restrict__ agg, const float* __restrict__ xin,
    const unsigned short* __restrict__ Whi, const unsigned short* __restrict__ Wlo,
    const float* __restrict__ bias, float* __restrict__ out,
    int relu, int nNodes) {
  int t = threadIdx.x;
  int wave = t >> 6;
  int lane = t & 63;
  int l15 = lane & 15;
  int lq  = lane >> 4;                       // 0..3
  int r0 = (blockIdx.x * 4 + wave) * 16;     // wave's first row

  const bf16x8* WhiV = reinterpret_cast<const bf16x8*>(Whi) + lane;
  const bf16x8* WloV = reinterpret_cast<const bf16x8*>(Wlo) + lane;

  f32x4 acc[8];
#pragma unroll
  for (int i = 0; i < 8; i++) acc[i] = (f32x4){0.f, 0.f, 0.f, 0.f};

  int arow = r0 + l15;
  if (arow >= nNodes) arow = nNodes - 1;     // clamp; masked at write

#pragma unroll
  for (int kc = 0; kc < 8; kc++) {
    const float* abase = (kc < 4) ? agg : xin;
    int k128 = (kc & 3) * 32 + lq * 8;
    const float* ap = abase + (size_t)arow * NCH + k128;
    float4 v0 = *reinterpret_cast<const float4*>(ap);
    float4 v1 = *reinterpret_cast<const float4*>(ap + 4);
    float av[8] = {v0.x, v0.y, v0.z, v0.w, v1.x, v1.y, v1.z, v1.w};
    bf16x8 ahi, alo;
#pragma unroll
    for (int i = 0; i < 8; i++) {
      unsigned u = __float_as_uint(av[i]);
      float fhi = __uint_as_float(u & 0xFFFF0000u);
      float flo = av[i] - fhi;
      ahi[i] = (short)(u >> 16);
      alo[i] = (short)(__float_as_uint(flo) >> 16);
    }
#pragma unroll
    for (int nt = 0; nt < 8; nt++) {
      int fidx = (kc * 8 + nt) * 64;         // + lane folded into WhiV/WloV
      bf16x8 bhi = WhiV[fidx];
      bf16x8 blo = WloV[fidx];
      acc[nt] = __builtin_amdgcn_mfma_f32_16x16x32_bf16(ahi, bhi, acc[nt], 0, 0, 0);
      acc[nt] = __builtin_amdgcn_mfma_f32_16x16x32_bf16(ahi, blo, acc[nt], 0, 0, 0);
      acc[nt] = __builtin_amdgcn_mfma_f32_16x16x32_bf16(alo, bhi, acc[nt], 0, 0, 0);
    }
  }

#pragma unroll
  for (int nt = 0; nt < 8; nt++) {
    int col = nt * 16 + l15;
    float bv = bias[col];
#pragma unroll
    for (int i = 0; i < 4; i++) {
      int row = r0 + lq * 4 + i;
      if (row < nNodes) {
        float v = acc[nt][i] + bv;
        if (relu) v = fmaxf(v, 0.f);
        out[(size_t)row * NCH + col] = v;
      }
    }
  }
}

extern "C" void kernel_launch(void* const* d_in, const int* in_sizes, int n_in,
                              void* d_out, int out_size, void* d_ws, size_t ws_size,
                              hipStream_t stream) {
  const float* x   = (const float*)d_in[0];
  const int*   ei  = (const int*)d_in[1];
  const float* W1l = (const float*)d_in[2];
  const float* W1r = (const float*)d_in[3];
  const float* b1  = (const float*)d_in[4];
  const float* W2l = (const float*)d_in[5];
  const float* W2r = (const float*)d_in[6];
  const float* b2  = (const float*)d_in[7];
  float* out = (float*)d_out;

  const int nE = in_sizes[1] / 2;     // 800000
  const int nN = in_sizes[0] / NCH;   // 50000
  const int* src = ei;
  const int* dst = ei + nE;

  size_t featBytes = (size_t)nN * NCH * sizeof(float);   // 25.6 MB
  size_t nodeInts  = (size_t)(nN + 1) * sizeof(int);
  size_t wBytes    = (size_t)128 * 256 * sizeof(unsigned short);  // 64 KB
  const int nChunks = (nN + SCAN_CHUNK - 1) / SCAN_CHUNK;         // 49

  char* ws = (char*)d_ws;
  float* A         = (float*)ws;                         ws += featBytes;
  float* B         = (float*)ws;                         ws += featBytes;
  int*   deg       = (int*)ws;                           ws += nodeInts;
  int*   startRow  = (int*)ws;                           ws += nodeInts;
  int*   cursor    = (int*)ws;                           ws += nodeInts;
  float* invdeg    = (float*)ws;                         ws += nodeInts;
  int*   srcSorted = (int*)ws;                           ws += (size_t)nE * sizeof(int);
  unsigned short* W1hi = (unsigned short*)ws;            ws += wBytes;
  unsigned short* W1lo = (unsigned short*)ws;            ws += wBytes;
  unsigned short* W2hi = (unsigned short*)ws;            ws += wBytes;
  unsigned short* W2lo = (unsigned short*)ws;            ws += wBytes;
  int*   chunkSum  = (int*)ws;                           ws += (size_t)nChunks * sizeof(int);

  // ---- CSR build + weight prep ----
  hipMemsetAsync(deg, 0, (size_t)nN * sizeof(int), stream);
  hipMemsetAsync(cursor, 0, (size_t)nN * sizeof(int), stream);
  k_deg<<<(nE + 255) / 256, 256, 0, stream>>>(dst, deg, nE);
  k_chunksum<<<nChunks, 256, 0, stream>>>(deg, chunkSum, nN);
  k_finalize<<<nChunks, 256, 0, stream>>>(deg, chunkSum, startRow, invdeg, nN);
  k_place<<<(nE + 255) / 256, 256, 0, stream>>>(src, dst, startRow, cursor, srcSorted, nE);
  k_prepW<<<(32768 + 255) / 256, 256, 0, stream>>>(W1l, W1r, W1hi, W1lo);
  k_prepW<<<(32768 + 255) / 256, 256, 0, stream>>>(W2l, W2r, W2hi, W2lo);

  int gatherBlocks = (nN * 32 + 255) / 256;
  int linBlocks = (nN + 63) / 64;

  // ---- layer 1 ----
  k_gather<<<gatherBlocks, 256, 0, stream>>>(x, srcSorted, startRow, invdeg, A, nN);
  k_linear_mfma<<<linBlocks, 256, 0, stream>>>(A, x, W1hi, W1lo, b1, B, 1, nN);

  // ---- layer 2 ----
  k_gather<<<gatherBlocks, 256, 0, stream>>>(B, srcSorted, startRow, invdeg, A, nN);
  k_linear_mfma<<<linBlocks, 256, 0, stream>>>(A, B, W2hi, W2lo, b2, out, 0, nN);
}

// Round 6
// 213.235 us; speedup vs baseline: 16.2563x; 1.2594x over previous
//
#include <hip/hip_runtime.h>

#define NCH 128
#define SCAN_CHUNK 1024

typedef __attribute__((ext_vector_type(8))) short bf16x8;
typedef __attribute__((ext_vector_type(4))) float f32x4;

__device__ __forceinline__ unsigned short f2bf_rne(float f) {
  unsigned u = __float_as_uint(f);
  unsigned r = u + 0x7FFF + ((u >> 16) & 1);
  return (unsigned short)(r >> 16);
}

// ---- degree histogram (int) -------------------------------------------------
__global__ __launch_bounds__(256) void k_deg(const int* __restrict__ dst,
                                             int* __restrict__ deg, int nE) {
  int e = blockIdx.x * 256 + threadIdx.x;
  if (e < nE) atomicAdd(&deg[dst[e]], 1);
}

// ---- hierarchical scan, phase 1: per-1024-chunk sums ------------------------
__global__ __launch_bounds__(256) void k_chunksum(const int* __restrict__ deg,
                                                  int* __restrict__ chunkSum, int nN) {
  int t = threadIdx.x;
  int base = blockIdx.x * SCAN_CHUNK + t * 4;
  int s = 0;
  if (base < nN) {
    int4 d = *reinterpret_cast<const int4*>(deg + base);
    s = d.x + d.y + d.z + d.w;
  }
  for (int off = 32; off; off >>= 1) s += __shfl_down(s, off);
  __shared__ int red[4];
  if ((t & 63) == 0) red[t >> 6] = s;
  __syncthreads();
  if (t == 0) chunkSum[blockIdx.x] = red[0] + red[1] + red[2] + red[3];
}

// ---- hierarchical scan, phase 2: per-chunk exclusive scan + offset ----------
__global__ __launch_bounds__(256) void k_finalize(const int* __restrict__ deg,
                                                  const int* __restrict__ chunkSum,
                                                  int* __restrict__ start,
                                                  float* __restrict__ invdeg, int nN) {
  int b = blockIdx.x, t = threadIdx.x;
  int base = b * SCAN_CHUNK + t * 4;

  __shared__ int s_coff;
  if (t < 64) {
    int v = (t < b) ? chunkSum[t] : 0;
    for (int off = 32; off; off >>= 1) v += __shfl_down(v, off);
    if (t == 0) s_coff = v;
  }

  int4 d = make_int4(0, 0, 0, 0);
  if (base < nN) d = *reinterpret_cast<const int4*>(deg + base);
  int s = d.x + d.y + d.z + d.w;

  __shared__ int ts[256];
  ts[t] = s;
  __syncthreads();
  for (int off = 1; off < 256; off <<= 1) {
    int v = (t >= off) ? ts[t - off] : 0;
    __syncthreads();
    ts[t] += v;
    __syncthreads();
  }

  if (base < nN) {
    int run = s_coff + ts[t] - s;
    int dv[4] = {d.x, d.y, d.z, d.w};
#pragma unroll
    for (int j = 0; j < 4; j++) {
      start[base + j] = run;
      invdeg[base + j] = 1.0f / fmaxf((float)dv[j], 1.0f);
      run += dv[j];
    }
  }
  if (b == gridDim.x - 1 && t == 255) start[nN] = s_coff + ts[255];
}

// ---- place edges into dst-sorted order (CSR) --------------------------------
__global__ __launch_bounds__(256) void k_place(const int* __restrict__ src,
                                               const int* __restrict__ dst,
                                               const int* __restrict__ start,
                                               int* __restrict__ cursor,
                                               int* __restrict__ srcSorted, int nE) {
  int e = blockIdx.x * 256 + threadIdx.x;
  if (e >= nE) return;
  int d = dst[e];
  int pos = start[d] + atomicAdd(&cursor[d], 1);
  srcSorted[pos] = src[e];
}

// ---- x (fp32 row-major) -> bf16 row-major, RNE ------------------------------
__global__ __launch_bounds__(256) void k_prepX(const float* __restrict__ x,
                                               unsigned short* __restrict__ xbf,
                                               int n8) {
  int i = blockIdx.x * 256 + threadIdx.x;   // one thread per 8 elements
  if (i >= n8) return;
  const float4* p = reinterpret_cast<const float4*>(x + (size_t)i * 8);
  float4 v0 = p[0], v1 = p[1];
  uint4 o;
  o.x = (unsigned)f2bf_rne(v0.x) | ((unsigned)f2bf_rne(v0.y) << 16);
  o.y = (unsigned)f2bf_rne(v0.z) | ((unsigned)f2bf_rne(v0.w) << 16);
  o.z = (unsigned)f2bf_rne(v1.x) | ((unsigned)f2bf_rne(v1.y) << 16);
  o.w = (unsigned)f2bf_rne(v1.z) | ((unsigned)f2bf_rne(v1.w) << 16);
  *reinterpret_cast<uint4*>(xbf + (size_t)i * 8) = o;
}

// ---- gather-mean over bf16 rows: aggbf[n] = bf16(mean x[src]) ---------------
// 16 lanes/node, 16B (8 bf16) per lane; fp32 accumulation; unroll x4.
#define ACC8(v)                                          \
  a0 += __uint_as_float((v).x << 16);                    \
  a1 += __uint_as_float((v).x & 0xFFFF0000u);            \
  a2 += __uint_as_float((v).y << 16);                    \
  a3 += __uint_as_float((v).y & 0xFFFF0000u);            \
  a4 += __uint_as_float((v).z << 16);                    \
  a5 += __uint_as_float((v).z & 0xFFFF0000u);            \
  a6 += __uint_as_float((v).w << 16);                    \
  a7 += __uint_as_float((v).w & 0xFFFF0000u);

__global__ __launch_bounds__(256) void k_gather(const unsigned short* __restrict__ xbf,
                                                const int* __restrict__ srcSorted,
                                                const int* __restrict__ start,
                                                const float* __restrict__ invdeg,
                                                unsigned short* __restrict__ aggbf,
                                                int nN) {
  int gid = blockIdx.x * 256 + threadIdx.x;
  int node = gid >> 4;
  if (node >= nN) return;
  int c = (gid & 15) << 3;                   // 8 channels per lane
  const unsigned short* xb = xbf + c;
  int s0 = start[node], s1 = start[node + 1];
  float a0 = 0.f, a1 = 0.f, a2 = 0.f, a3 = 0.f,
        a4 = 0.f, a5 = 0.f, a6 = 0.f, a7 = 0.f;
  int i = s0;
  for (; i + 4 <= s1; i += 4) {
    int sa = srcSorted[i],     sb = srcSorted[i + 1];
    int sc = srcSorted[i + 2], sd = srcSorted[i + 3];
    uint4 va = *reinterpret_cast<const uint4*>(xb + (size_t)sa * NCH);
    uint4 vb = *reinterpret_cast<const uint4*>(xb + (size_t)sb * NCH);
    uint4 vc = *reinterpret_cast<const uint4*>(xb + (size_t)sc * NCH);
    uint4 vd = *reinterpret_cast<const uint4*>(xb + (size_t)sd * NCH);
    ACC8(va) ACC8(vb) ACC8(vc) ACC8(vd)
  }
  for (; i < s1; i++) {
    int s = srcSorted[i];
    uint4 v = *reinterpret_cast<const uint4*>(xb + (size_t)s * NCH);
    ACC8(v)
  }
  float idg = invdeg[node];
  uint4 o;
  o.x = (unsigned)f2bf_rne(a0 * idg) | ((unsigned)f2bf_rne(a1 * idg) << 16);
  o.y = (unsigned)f2bf_rne(a2 * idg) | ((unsigned)f2bf_rne(a3 * idg) << 16);
  o.z = (unsigned)f2bf_rne(a4 * idg) | ((unsigned)f2bf_rne(a5 * idg) << 16);
  o.w = (unsigned)f2bf_rne(a6 * idg) | ((unsigned)f2bf_rne(a7 * idg) << 16);
  *reinterpret_cast<uint4*>(aggbf + (size_t)node * NCH + c) = o;
}

// ---- prep: fragment-ordered split-bf16 weights (unchanged, proven) ----------
__global__ __launch_bounds__(256) void k_prepW(const float* __restrict__ Wl,
                                               const float* __restrict__ Wr,
                                               unsigned short* __restrict__ WhiF,
                                               unsigned short* __restrict__ WloF) {
  int i = blockIdx.x * 256 + threadIdx.x;  // 32768 elements
  if (i >= 32768) return;
  int kc   = i >> 12;
  int r    = i & 4095;
  int nt   = r >> 9;
  int r2   = r & 511;
  int lane = r2 >> 3;
  int e    = r2 & 7;
  int j = nt * 16 + (lane & 15);
  int k = kc * 32 + (lane >> 4) * 8 + e;
  float w = (k < 128) ? Wl[j * 128 + k] : Wr[j * 128 + (k - 128)];
  unsigned u = __float_as_uint(w);
  float fhi = __uint_as_float(u & 0xFFFF0000u);
  float flo = w - fhi;
  WhiF[i] = (unsigned short)(u >> 16);
  WloF[i] = (unsigned short)(__float_as_uint(flo) >> 16);
}

// ---- MFMA linear: out = [relu]( [agg|x]_bf16 @ (Whi+Wlo) + b ) --------------
// A is bf16 directly (no split, no conversion VALU); W split hi/lo for precision.
__global__ __launch_bounds__(256, 4) void k_linear_mfma(
    const unsigned short* __restrict__ aggbf, const unsigned short* __restrict__ xinbf,
    const unsigned short* __restrict__ Whi, const unsigned short* __restrict__ Wlo,
    const float* __restrict__ bias, float* __restrict__ outF,
    unsigned short* __restrict__ outBf, int relu, int nNodes) {
  int t = threadIdx.x;
  int wave = t >> 6;
  int lane = t & 63;
  int l15 = lane & 15;
  int lq  = lane >> 4;                       // 0..3
  int r0 = (blockIdx.x * 4 + wave) * 16;     // wave's first row

  const bf16x8* WhiV = reinterpret_cast<const bf16x8*>(Whi) + lane;
  const bf16x8* WloV = reinterpret_cast<const bf16x8*>(Wlo) + lane;

  f32x4 acc[8];
#pragma unroll
  for (int i = 0; i < 8; i++) acc[i] = (f32x4){0.f, 0.f, 0.f, 0.f};

  int arow = r0 + l15;
  if (arow >= nNodes) arow = nNodes - 1;     // clamp; masked at write

#pragma unroll
  for (int kc = 0; kc < 8; kc++) {
    const unsigned short* ab = (kc < 4) ? aggbf : xinbf;
    int k128 = (kc & 3) * 32 + lq * 8;
    bf16x8 a = *reinterpret_cast<const bf16x8*>(ab + (size_t)arow * NCH + k128);
#pragma unroll
    for (int nt = 0; nt < 8; nt++) {
      int fidx = (kc * 8 + nt) * 64;         // + lane folded into WhiV/WloV
      bf16x8 bhi = WhiV[fidx];
      bf16x8 blo = WloV[fidx];
      acc[nt] = __builtin_amdgcn_mfma_f32_16x16x32_bf16(a, bhi, acc[nt], 0, 0, 0);
      acc[nt] = __builtin_amdgcn_mfma_f32_16x16x32_bf16(a, blo, acc[nt], 0, 0, 0);
    }
  }

#pragma unroll
  for (int nt = 0; nt < 8; nt++) {
    int col = nt * 16 + l15;
    float bv = bias[col];
#pragma unroll
    for (int i = 0; i < 4; i++) {
      int row = r0 + lq * 4 + i;
      if (row < nNodes) {
        float v = acc[nt][i] + bv;
        if (relu) v = fmaxf(v, 0.f);
        if (outBf) outBf[(size_t)row * NCH + col] = f2bf_rne(v);
        else       outF[(size_t)row * NCH + col] = v;
      }
    }
  }
}

extern "C" void kernel_launch(void* const* d_in, const int* in_sizes, int n_in,
                              void* d_out, int out_size, void* d_ws, size_t ws_size,
                              hipStream_t stream) {
  const float* x   = (const float*)d_in[0];
  const int*   ei  = (const int*)d_in[1];
  const float* W1l = (const float*)d_in[2];
  const float* W1r = (const float*)d_in[3];
  const float* b1  = (const float*)d_in[4];
  const float* W2l = (const float*)d_in[5];
  const float* W2r = (const float*)d_in[6];
  const float* b2  = (const float*)d_in[7];
  float* out = (float*)d_out;

  const int nE = in_sizes[1] / 2;     // 800000
  const int nN = in_sizes[0] / NCH;   // 50000
  const int* src = ei;
  const int* dst = ei + nE;

  size_t bfBytes   = (size_t)nN * NCH * sizeof(unsigned short);   // 12.8 MB
  size_t nodeInts  = (((size_t)(nN + 1) * sizeof(int)) + 255) & ~(size_t)255;
  size_t wBytes    = (size_t)128 * 256 * sizeof(unsigned short);  // 64 KB
  const int nChunks = (nN + SCAN_CHUNK - 1) / SCAN_CHUNK;         // 49

  char* ws = (char*)d_ws;
  unsigned short* xbf   = (unsigned short*)ws;           ws += bfBytes;
  unsigned short* aggbf = (unsigned short*)ws;           ws += bfBytes;
  unsigned short* hbf   = (unsigned short*)ws;           ws += bfBytes;
  int*   deg       = (int*)ws;                           ws += nodeInts;
  int*   startRow  = (int*)ws;                           ws += nodeInts;
  int*   cursor    = (int*)ws;                           ws += nodeInts;
  float* invdeg    = (float*)ws;                         ws += nodeInts;
  int*   srcSorted = (int*)ws;                           ws += (size_t)nE * sizeof(int);
  unsigned short* W1hi = (unsigned short*)ws;            ws += wBytes;
  unsigned short* W1lo = (unsigned short*)ws;            ws += wBytes;
  unsigned short* W2hi = (unsigned short*)ws;            ws += wBytes;
  unsigned short* W2lo = (unsigned short*)ws;            ws += wBytes;
  int*   chunkSum  = (int*)ws;                           ws += (size_t)nChunks * sizeof(int);

  // ---- CSR build + prep ----
  hipMemsetAsync(deg, 0, (size_t)nN * sizeof(int), stream);
  hipMemsetAsync(cursor, 0, (size_t)nN * sizeof(int), stream);
  k_deg<<<(nE + 255) / 256, 256, 0, stream>>>(dst, deg, nE);
  k_chunksum<<<nChunks, 256, 0, stream>>>(deg, chunkSum, nN);
  k_finalize<<<nChunks, 256, 0, stream>>>(deg, chunkSum, startRow, invdeg, nN);
  k_place<<<(nE + 255) / 256, 256, 0, stream>>>(src, dst, startRow, cursor, srcSorted, nE);
  k_prepW<<<(32768 + 255) / 256, 256, 0, stream>>>(W1l, W1r, W1hi, W1lo);
  k_prepW<<<(32768 + 255) / 256, 256, 0, stream>>>(W2l, W2r, W2hi, W2lo);
  {
    int n8 = nN * NCH / 8;
    k_prepX<<<(n8 + 255) / 256, 256, 0, stream>>>(x, xbf, n8);
  }

  int gatherBlocks = (nN * 16 + 255) / 256;
  int linBlocks = (nN + 63) / 64;

  // ---- layer 1 ----
  k_gather<<<gatherBlocks, 256, 0, stream>>>(xbf, srcSorted, startRow, invdeg, aggbf, nN);
  k_linear_mfma<<<linBlocks, 256, 0, stream>>>(aggbf, xbf, W1hi, W1lo, b1,
                                               nullptr, hbf, 1, nN);

  // ---- layer 2 ----
  k_gather<<<gatherBlocks, 256, 0, stream>>>(hbf, srcSorted, startRow, invdeg, aggbf, nN);
  k_linear_mfma<<<linBlocks, 256, 0, stream>>>(aggbf, hbf, W2hi, W2lo, b2,
                                               out, nullptr, 0, nN);
}

// Round 7
// 164.461 us; speedup vs baseline: 21.0775x; 1.2966x over previous
//
#include <hip/hip_runtime.h>

#define NCH 128
#define MAXBKT 512          // supports nN <= 65536 at 128 nodes/bucket
#define BKT_SHIFT 7         // 128 nodes per bucket
#define BKT_NODES 128
#define BIN_BATCH 4096      // edges per k_bin block (16/thread)

typedef __attribute__((ext_vector_type(8))) short bf16x8;
typedef __attribute__((ext_vector_type(4))) float f32x4;

__device__ __forceinline__ unsigned short f2bf_rne(float f) {
  unsigned u = __float_as_uint(f);
  unsigned r = u + 0x7FFF + ((u >> 16) & 1);
  return (unsigned short)(r >> 16);
}

// ---- bucket histogram: LDS-binned, few global atomics -----------------------
__global__ __launch_bounds__(256) void k_bkthist(const int* __restrict__ dst,
                                                 int* __restrict__ bktCount,
                                                 int nE, int nBkt) {
  __shared__ int h[MAXBKT];
  int t = threadIdx.x;
  h[t] = 0; h[t + 256] = 0;
  __syncthreads();
  for (int e = blockIdx.x * 256 + t; e < nE; e += gridDim.x * 256)
    atomicAdd(&h[dst[e] >> BKT_SHIFT], 1);
  __syncthreads();
  for (int i = t; i < nBkt; i += 256)
    if (h[i]) atomicAdd(&bktCount[i], h[i]);
}

// ---- scan bucket counts -> bktBase[0..nBkt] ---------------------------------
__global__ __launch_bounds__(512) void k_bktscan(const int* __restrict__ bktCount,
                                                 int* __restrict__ bktBase, int nBkt) {
  __shared__ int sc[512];
  int t = threadIdx.x;
  int v = (t < nBkt) ? bktCount[t] : 0;
  sc[t] = v;
  __syncthreads();
  for (int off = 1; off < 512; off <<= 1) {
    int u = (t >= off) ? sc[t - off] : 0;
    __syncthreads();
    sc[t] += u;
    __syncthreads();
  }
  if (t < nBkt) bktBase[t] = sc[t] - v;
  if (t == 511) bktBase[nBkt] = sc[511];
}

// ---- bin edges into bucket regions (contiguous runs per block,bucket) -------
__global__ __launch_bounds__(256) void k_bin(const int* __restrict__ src,
                                             const int* __restrict__ dst,
                                             const int* __restrict__ bktBase,
                                             int* __restrict__ bktCursor,
                                             uint2* __restrict__ binned,
                                             int nE, int nBkt) {
  __shared__ int hist[MAXBKT];
  __shared__ int boff[MAXBKT];
  int t = threadIdx.x;
  hist[t] = 0; hist[t + 256] = 0;
  __syncthreads();

  int eb = blockIdx.x * BIN_BATCH;
  uint2 pr[16];
  int rk[16];
#pragma unroll
  for (int i = 0; i < 16; i++) {
    int e = eb + t + i * 256;
    if (e < nE) {
      pr[i] = make_uint2((unsigned)src[e], (unsigned)dst[e]);
      rk[i] = atomicAdd(&hist[pr[i].y >> BKT_SHIFT], 1);
    } else rk[i] = -1;
  }
  __syncthreads();
  for (int i = t; i < nBkt; i += 256)
    boff[i] = hist[i] ? atomicAdd(&bktCursor[i], hist[i]) : 0;
  __syncthreads();
#pragma unroll
  for (int i = 0; i < 16; i++) {
    if (rk[i] >= 0) {
      int b = pr[i].y >> BKT_SHIFT;
      binned[bktBase[b] + boff[b] + rk[i]] = pr[i];
    }
  }
}

// ---- per-bucket CSR build + placement (all LDS atomics, localized writes) ---
__global__ __launch_bounds__(256) void k_build(const uint2* __restrict__ binned,
                                               const int* __restrict__ bktBase,
                                               int* __restrict__ start,
                                               float* __restrict__ invdeg,
                                               int* __restrict__ srcSorted,
                                               int nN, int nE) {
  __shared__ int cnt[BKT_NODES];
  __shared__ int sc[BKT_NODES];
  __shared__ int cur[BKT_NODES];
  int b = blockIdx.x, t = threadIdx.x;
  int base = b << BKT_SHIFT;
  int e0 = bktBase[b], e1 = bktBase[b + 1];

  if (t < BKT_NODES) { cnt[t] = 0; cur[t] = 0; }
  __syncthreads();
  for (int i = e0 + t; i < e1; i += 256)
    atomicAdd(&cnt[binned[i].y - base], 1);
  __syncthreads();
  if (t < BKT_NODES) sc[t] = cnt[t];
  __syncthreads();
  for (int off = 1; off < BKT_NODES; off <<= 1) {
    int u = (t < BKT_NODES && t >= off) ? sc[t - off] : 0;
    __syncthreads();
    if (t < BKT_NODES && t >= off) sc[t] += u;
    __syncthreads();
  }
  if (t < BKT_NODES) {
    int n = base + t;
    if (n < nN) {
      start[n] = e0 + sc[t] - cnt[t];
      invdeg[n] = 1.0f / fmaxf((float)cnt[t], 1.0f);
    }
  }
  if (b == 0 && t == 0) start[nN] = nE;
  __syncthreads();
  for (int i = e0 + t; i < e1; i += 256) {
    uint2 p = binned[i];
    int ld = p.y - base;
    int pos = e0 + sc[ld] - cnt[ld] + atomicAdd(&cur[ld], 1);
    srcSorted[pos] = (int)p.x;
  }
}

// ---- x (fp32 row-major) -> bf16 row-major, RNE ------------------------------
__global__ __launch_bounds__(256) void k_prepX(const float* __restrict__ x,
                                               unsigned short* __restrict__ xbf,
                                               int n8) {
  int i = blockIdx.x * 256 + threadIdx.x;
  if (i >= n8) return;
  const float4* p = reinterpret_cast<const float4*>(x + (size_t)i * 8);
  float4 v0 = p[0], v1 = p[1];
  uint4 o;
  o.x = (unsigned)f2bf_rne(v0.x) | ((unsigned)f2bf_rne(v0.y) << 16);
  o.y = (unsigned)f2bf_rne(v0.z) | ((unsigned)f2bf_rne(v0.w) << 16);
  o.z = (unsigned)f2bf_rne(v1.x) | ((unsigned)f2bf_rne(v1.y) << 16);
  o.w = (unsigned)f2bf_rne(v1.z) | ((unsigned)f2bf_rne(v1.w) << 16);
  *reinterpret_cast<uint4*>(xbf + (size_t)i * 8) = o;
}

// ---- gather-mean over bf16 rows ---------------------------------------------
#define ACC8(v)                                          \
  a0 += __uint_as_float((v).x << 16);                    \
  a1 += __uint_as_float((v).x & 0xFFFF0000u);            \
  a2 += __uint_as_float((v).y << 16);                    \
  a3 += __uint_as_float((v).y & 0xFFFF0000u);            \
  a4 += __uint_as_float((v).z << 16);                    \
  a5 += __uint_as_float((v).z & 0xFFFF0000u);            \
  a6 += __uint_as_float((v).w << 16);                    \
  a7 += __uint_as_float((v).w & 0xFFFF0000u);

__global__ __launch_bounds__(256) void k_gather(const unsigned short* __restrict__ xbf,
                                                const int* __restrict__ srcSorted,
                                                const int* __restrict__ start,
                                                const float* __restrict__ invdeg,
                                                unsigned short* __restrict__ aggbf,
                                                int nN) {
  int gid = blockIdx.x * 256 + threadIdx.x;
  int node = gid >> 4;
  if (node >= nN) return;
  int c = (gid & 15) << 3;
  const unsigned short* xb = xbf + c;
  int s0 = start[node], s1 = start[node + 1];
  float a0 = 0.f, a1 = 0.f, a2 = 0.f, a3 = 0.f,
        a4 = 0.f, a5 = 0.f, a6 = 0.f, a7 = 0.f;
  int i = s0;
  for (; i + 4 <= s1; i += 4) {
    int sa = srcSorted[i],     sb = srcSorted[i + 1];
    int sc_ = srcSorted[i + 2], sd = srcSorted[i + 3];
    uint4 va = *reinterpret_cast<const uint4*>(xb + (size_t)sa * NCH);
    uint4 vb = *reinterpret_cast<const uint4*>(xb + (size_t)sb * NCH);
    uint4 vc = *reinterpret_cast<const uint4*>(xb + (size_t)sc_ * NCH);
    uint4 vd = *reinterpret_cast<const uint4*>(xb + (size_t)sd * NCH);
    ACC8(va) ACC8(vb) ACC8(vc) ACC8(vd)
  }
  for (; i < s1; i++) {
    int s = srcSorted[i];
    uint4 v = *reinterpret_cast<const uint4*>(xb + (size_t)s * NCH);
    ACC8(v)
  }
  float idg = invdeg[node];
  uint4 o;
  o.x = (unsigned)f2bf_rne(a0 * idg) | ((unsigned)f2bf_rne(a1 * idg) << 16);
  o.y = (unsigned)f2bf_rne(a2 * idg) | ((unsigned)f2bf_rne(a3 * idg) << 16);
  o.z = (unsigned)f2bf_rne(a4 * idg) | ((unsigned)f2bf_rne(a5 * idg) << 16);
  o.w = (unsigned)f2bf_rne(a6 * idg) | ((unsigned)f2bf_rne(a7 * idg) << 16);
  *reinterpret_cast<uint4*>(aggbf + (size_t)node * NCH + c) = o;
}

// ---- prep: fragment-ordered split-bf16 weights ------------------------------
__global__ __launch_bounds__(256) void k_prepW(const float* __restrict__ Wl,
                                               const float* __restrict__ Wr,
                                               unsigned short* __restrict__ WhiF,
                                               unsigned short* __restrict__ WloF) {
  int i = blockIdx.x * 256 + threadIdx.x;
  if (i >= 32768) return;
  int kc   = i >> 12;
  int r    = i & 4095;
  int nt   = r >> 9;
  int r2   = r & 511;
  int lane = r2 >> 3;
  int e    = r2 & 7;
  int j = nt * 16 + (lane & 15);
  int k = kc * 32 + (lane >> 4) * 8 + e;
  float w = (k < 128) ? Wl[j * 128 + k] : Wr[j * 128 + (k - 128)];
  unsigned u = __float_as_uint(w);
  float fhi = __uint_as_float(u & 0xFFFF0000u);
  float flo = w - fhi;
  WhiF[i] = (unsigned short)(u >> 16);
  WloF[i] = (unsigned short)(__float_as_uint(flo) >> 16);
}

// ---- MFMA linear: out = [relu]( [agg|x]_bf16 @ (Whi+Wlo) + b ) --------------
__global__ __launch_bounds__(256, 4) void k_linear_mfma(
    const unsigned short* __restrict__ aggbf, const unsigned short* __restrict__ xinbf,
    const unsigned short* __restrict__ Whi, const unsigned short* __restrict__ Wlo,
    const float* __restrict__ bias, float* __restrict__ outF,
    unsigned short* __restrict__ outBf, int relu, int nNodes) {
  int t = threadIdx.x;
  int wave = t >> 6;
  int lane = t & 63;
  int l15 = lane & 15;
  int lq  = lane >> 4;
  int r0 = (blockIdx.x * 4 + wave) * 16;

  const bf16x8* WhiV = reinterpret_cast<const bf16x8*>(Whi) + lane;
  const bf16x8* WloV = reinterpret_cast<const bf16x8*>(Wlo) + lane;

  f32x4 acc[8];
#pragma unroll
  for (int i = 0; i < 8; i++) acc[i] = (f32x4){0.f, 0.f, 0.f, 0.f};

  int arow = r0 + l15;
  if (arow >= nNodes) arow = nNodes - 1;

#pragma unroll
  for (int kc = 0; kc < 8; kc++) {
    const unsigned short* ab = (kc < 4) ? aggbf : xinbf;
    int k128 = (kc & 3) * 32 + lq * 8;
    bf16x8 a = *reinterpret_cast<const bf16x8*>(ab + (size_t)arow * NCH + k128);
#pragma unroll
    for (int nt = 0; nt < 8; nt++) {
      int fidx = (kc * 8 + nt) * 64;
      bf16x8 bhi = WhiV[fidx];
      bf16x8 blo = WloV[fidx];
      acc[nt] = __builtin_amdgcn_mfma_f32_16x16x32_bf16(a, bhi, acc[nt], 0, 0, 0);
      acc[nt] = __builtin_amdgcn_mfma_f32_16x16x32_bf16(a, blo, acc[nt], 0, 0, 0);
    }
  }

#pragma unroll
  for (int nt = 0; nt < 8; nt++) {
    int col = nt * 16 + l15;
    float bv = bias[col];
#pragma unroll
    for (int i = 0; i < 4; i++) {
      int row = r0 + lq * 4 + i;
      if (row < nNodes) {
        float v = acc[nt][i] + bv;
        if (relu) v = fmaxf(v, 0.f);
        if (outBf) outBf[(size_t)row * NCH + col] = f2bf_rne(v);
        else       outF[(size_t)row * NCH + col] = v;
      }
    }
  }
}

extern "C" void kernel_launch(void* const* d_in, const int* in_sizes, int n_in,
                              void* d_out, int out_size, void* d_ws, size_t ws_size,
                              hipStream_t stream) {
  const float* x   = (const float*)d_in[0];
  const int*   ei  = (const int*)d_in[1];
  const float* W1l = (const float*)d_in[2];
  const float* W1r = (const float*)d_in[3];
  const float* b1  = (const float*)d_in[4];
  const float* W2l = (const float*)d_in[5];
  const float* W2r = (const float*)d_in[6];
  const float* b2  = (const float*)d_in[7];
  float* out = (float*)d_out;

  const int nE = in_sizes[1] / 2;     // 800000
  const int nN = in_sizes[0] / NCH;   // 50000
  const int* src = ei;
  const int* dst = ei + nE;
  const int nBkt = (nN + BKT_NODES - 1) >> BKT_SHIFT;   // 391

  size_t bfBytes = (size_t)nN * NCH * sizeof(unsigned short);   // 12.8 MB
  size_t wBytes  = (size_t)128 * 256 * sizeof(unsigned short);  // 64 KB
  auto align256 = [](size_t v) { return (v + 255) & ~(size_t)255; };

  char* ws = (char*)d_ws;
  unsigned short* xbf   = (unsigned short*)ws;  ws += bfBytes;
  unsigned short* aggbf = (unsigned short*)ws;  ws += bfBytes;
  unsigned short* hbf   = (unsigned short*)ws;  ws += bfBytes;
  uint2* binned    = (uint2*)ws;                ws += (size_t)nE * sizeof(uint2);
  int*   srcSorted = (int*)ws;                  ws += align256((size_t)nE * sizeof(int));
  int*   startRow  = (int*)ws;                  ws += align256((size_t)(nN + 1) * sizeof(int));
  float* invdeg    = (float*)ws;                ws += align256((size_t)nN * sizeof(float));
  int*   bktCount  = (int*)ws;                  ws += MAXBKT * sizeof(int);
  int*   bktCursor = (int*)ws;                  ws += MAXBKT * sizeof(int);
  int*   bktBase   = (int*)ws;                  ws += align256((MAXBKT + 1) * sizeof(int));
  unsigned short* W1hi = (unsigned short*)ws;   ws += wBytes;
  unsigned short* W1lo = (unsigned short*)ws;   ws += wBytes;
  unsigned short* W2hi = (unsigned short*)ws;   ws += wBytes;
  unsigned short* W2lo = (unsigned short*)ws;   ws += wBytes;

  // ---- CSR build (bucketed counting sort, LDS-aggregated atomics) ----
  hipMemsetAsync(bktCount, 0, 2 * MAXBKT * sizeof(int), stream);  // count+cursor
  k_bkthist<<<128, 256, 0, stream>>>(dst, bktCount, nE, nBkt);
  k_bktscan<<<1, 512, 0, stream>>>(bktCount, bktBase, nBkt);
  k_bin<<<(nE + BIN_BATCH - 1) / BIN_BATCH, 256, 0, stream>>>(src, dst, bktBase,
                                                              bktCursor, binned, nE, nBkt);
  k_build<<<nBkt, 256, 0, stream>>>(binned, bktBase, startRow, invdeg, srcSorted, nN, nE);

  // ---- weight / feature prep ----
  k_prepW<<<(32768 + 255) / 256, 256, 0, stream>>>(W1l, W1r, W1hi, W1lo);
  k_prepW<<<(32768 + 255) / 256, 256, 0, stream>>>(W2l, W2r, W2hi, W2lo);
  {
    int n8 = nN * NCH / 8;
    k_prepX<<<(n8 + 255) / 256, 256, 0, stream>>>(x, xbf, n8);
  }

  int gatherBlocks = (nN * 16 + 255) / 256;
  int linBlocks = (nN + 63) / 64;

  // ---- layer 1 ----
  k_gather<<<gatherBlocks, 256, 0, stream>>>(xbf, srcSorted, startRow, invdeg, aggbf, nN);
  k_linear_mfma<<<linBlocks, 256, 0, stream>>>(aggbf, xbf, W1hi, W1lo, b1,
                                               nullptr, hbf, 1, nN);

  // ---- layer 2 ----
  k_gather<<<gatherBlocks, 256, 0, stream>>>(hbf, srcSorted, startRow, invdeg, aggbf, nN);
  k_linear_mfma<<<linBlocks, 256, 0, stream>>>(aggbf, hbf, W2hi, W2lo, b2,
                                               out, nullptr, 0, nN);
}

// Round 8
// 158.758 us; speedup vs baseline: 21.8346x; 1.0359x over previous
//
#include <hip/hip_runtime.h>

#define NCH 128
#define MAXBKT 512          // supports nN <= 65536 at 128 nodes/bucket
#define BKT_SHIFT 7         // 128 nodes per bucket
#define BKT_NODES 128
#define BIN_BATCH 4096      // edges per k_bin block (16/thread)
#define NHIST 128           // k_bkthist grid (fixed)

typedef __attribute__((ext_vector_type(8))) short bf16x8;
typedef __attribute__((ext_vector_type(4))) float f32x4;

__device__ __forceinline__ unsigned short f2bf_rne(float f) {
  unsigned u = __float_as_uint(f);
  unsigned r = u + 0x7FFF + ((u >> 16) & 1);
  return (unsigned short)(r >> 16);
}

// ---- bucket histogram: per-block partials, NO global atomics, NO init -------
__global__ __launch_bounds__(256) void k_bkthist(const int* __restrict__ dst,
                                                 int* __restrict__ partial,
                                                 int nE, int nBkt) {
  __shared__ int h[MAXBKT];
  int t = threadIdx.x;
  h[t] = 0; h[t + 256] = 0;
  __syncthreads();
  for (int e = blockIdx.x * 256 + t; e < nE; e += gridDim.x * 256)
    atomicAdd(&h[dst[e] >> BKT_SHIFT], 1);
  __syncthreads();
  partial[blockIdx.x * MAXBKT + t] = h[t];
  partial[blockIdx.x * MAXBKT + t + 256] = h[t + 256];
}

// ---- sum partials + scan -> bktBase; also zero bktCursor (replaces memset) --
__global__ __launch_bounds__(512) void k_bktscan(const int* __restrict__ partial,
                                                 int* __restrict__ bktBase,
                                                 int* __restrict__ bktCursor, int nBkt) {
  __shared__ int sc[512];
  int t = threadIdx.x;
  int v = 0;
#pragma unroll 8
  for (int b = 0; b < NHIST; b++) v += partial[b * MAXBKT + t];
  sc[t] = v;
  __syncthreads();
  for (int off = 1; off < 512; off <<= 1) {
    int u = (t >= off) ? sc[t - off] : 0;
    __syncthreads();
    sc[t] += u;
    __syncthreads();
  }
  bktBase[t] = sc[t] - v;            // buckets >= nBkt have v=0; harmless
  if (t == 511) bktBase[512] = sc[511];
  bktCursor[t] = 0;
}

// ---- bin edges into bucket regions (contiguous runs per block,bucket) -------
__global__ __launch_bounds__(256) void k_bin(const int* __restrict__ src,
                                             const int* __restrict__ dst,
                                             const int* __restrict__ bktBase,
                                             int* __restrict__ bktCursor,
                                             uint2* __restrict__ binned,
                                             int nE, int nBkt) {
  __shared__ int hist[MAXBKT];
  __shared__ int boff[MAXBKT];
  int t = threadIdx.x;
  hist[t] = 0; hist[t + 256] = 0;
  __syncthreads();

  int eb = blockIdx.x * BIN_BATCH;
  uint2 pr[16];
  int rk[16];
#pragma unroll
  for (int i = 0; i < 16; i++) {
    int e = eb + t + i * 256;
    if (e < nE) {
      pr[i] = make_uint2((unsigned)src[e], (unsigned)dst[e]);
      rk[i] = atomicAdd(&hist[pr[i].y >> BKT_SHIFT], 1);
    } else rk[i] = -1;
  }
  __syncthreads();
  for (int i = t; i < nBkt; i += 256)
    boff[i] = hist[i] ? atomicAdd(&bktCursor[i], hist[i]) : 0;
  __syncthreads();
#pragma unroll
  for (int i = 0; i < 16; i++) {
    if (rk[i] >= 0) {
      int b = pr[i].y >> BKT_SHIFT;
      binned[bktBase[b] + boff[b] + rk[i]] = pr[i];
    }
  }
}

// ---- per-bucket CSR build + placement (all LDS atomics, localized writes) ---
__global__ __launch_bounds__(256) void k_build(const uint2* __restrict__ binned,
                                               const int* __restrict__ bktBase,
                                               int* __restrict__ start,
                                               float* __restrict__ invdeg,
                                               int* __restrict__ srcSorted,
                                               int nN, int nE) {
  __shared__ int cnt[BKT_NODES];
  __shared__ int sc[BKT_NODES];
  __shared__ int cur[BKT_NODES];
  int b = blockIdx.x, t = threadIdx.x;
  int base = b << BKT_SHIFT;
  int e0 = bktBase[b], e1 = bktBase[b + 1];

  if (t < BKT_NODES) { cnt[t] = 0; cur[t] = 0; }
  __syncthreads();
  for (int i = e0 + t; i < e1; i += 256)
    atomicAdd(&cnt[binned[i].y - base], 1);
  __syncthreads();
  if (t < BKT_NODES) sc[t] = cnt[t];
  __syncthreads();
  for (int off = 1; off < BKT_NODES; off <<= 1) {
    int u = (t < BKT_NODES && t >= off) ? sc[t - off] : 0;
    __syncthreads();
    if (t < BKT_NODES && t >= off) sc[t] += u;
    __syncthreads();
  }
  if (t < BKT_NODES) {
    int n = base + t;
    if (n < nN) {
      start[n] = e0 + sc[t] - cnt[t];
      invdeg[n] = 1.0f / fmaxf((float)cnt[t], 1.0f);
    }
  }
  if (b == 0 && t == 0) start[nN] = nE;
  __syncthreads();
  for (int i = e0 + t; i < e1; i += 256) {
    uint2 p = binned[i];
    int ld = p.y - base;
    int pos = e0 + sc[ld] - cnt[ld] + atomicAdd(&cur[ld], 1);
    srcSorted[pos] = (int)p.x;
  }
}

// ---- fused prep: x->bf16 AND both weight splits in ONE dispatch -------------
__device__ __forceinline__ void prepW_elem(const float* __restrict__ Wl,
                                           const float* __restrict__ Wr,
                                           unsigned short* __restrict__ WhiF,
                                           unsigned short* __restrict__ WloF, int i) {
  int kc   = i >> 12;
  int r    = i & 4095;
  int nt   = r >> 9;
  int r2   = r & 511;
  int lane = r2 >> 3;
  int e    = r2 & 7;
  int j = nt * 16 + (lane & 15);
  int k = kc * 32 + (lane >> 4) * 8 + e;
  float w = (k < 128) ? Wl[j * 128 + k] : Wr[j * 128 + (k - 128)];
  unsigned u = __float_as_uint(w);
  float fhi = __uint_as_float(u & 0xFFFF0000u);
  float flo = w - fhi;
  WhiF[i] = (unsigned short)(u >> 16);
  WloF[i] = (unsigned short)(__float_as_uint(flo) >> 16);
}

__global__ __launch_bounds__(256) void k_prep(const float* __restrict__ x,
                                              unsigned short* __restrict__ xbf,
                                              const float* __restrict__ W1l,
                                              const float* __restrict__ W1r,
                                              const float* __restrict__ W2l,
                                              const float* __restrict__ W2r,
                                              unsigned short* __restrict__ W1hi,
                                              unsigned short* __restrict__ W1lo,
                                              unsigned short* __restrict__ W2hi,
                                              unsigned short* __restrict__ W2lo,
                                              int n8) {
  int i = blockIdx.x * 256 + threadIdx.x;
  if (i < n8) {                       // n8 = nN*NCH/8, multiple of 256
    const float4* p = reinterpret_cast<const float4*>(x + (size_t)i * 8);
    float4 v0 = p[0], v1 = p[1];
    uint4 o;
    o.x = (unsigned)f2bf_rne(v0.x) | ((unsigned)f2bf_rne(v0.y) << 16);
    o.y = (unsigned)f2bf_rne(v0.z) | ((unsigned)f2bf_rne(v0.w) << 16);
    o.z = (unsigned)f2bf_rne(v1.x) | ((unsigned)f2bf_rne(v1.y) << 16);
    o.w = (unsigned)f2bf_rne(v1.z) | ((unsigned)f2bf_rne(v1.w) << 16);
    *reinterpret_cast<uint4*>(xbf + (size_t)i * 8) = o;
  } else {
    int j = i - n8;
    if (j < 32768)       prepW_elem(W1l, W1r, W1hi, W1lo, j);
    else if (j < 65536)  prepW_elem(W2l, W2r, W2hi, W2lo, j - 32768);
  }
}

// ---- gather-mean over bf16 rows ---------------------------------------------
#define ACC8(v)                                          \
  a0 += __uint_as_float((v).x << 16);                    \
  a1 += __uint_as_float((v).x & 0xFFFF0000u);            \
  a2 += __uint_as_float((v).y << 16);                    \
  a3 += __uint_as_float((v).y & 0xFFFF0000u);            \
  a4 += __uint_as_float((v).z << 16);                    \
  a5 += __uint_as_float((v).z & 0xFFFF0000u);            \
  a6 += __uint_as_float((v).w << 16);                    \
  a7 += __uint_as_float((v).w & 0xFFFF0000u);

__global__ __launch_bounds__(256) void k_gather(const unsigned short* __restrict__ xbf,
                                                const int* __restrict__ srcSorted,
                                                const int* __restrict__ start,
                                                const float* __restrict__ invdeg,
                                                unsigned short* __restrict__ aggbf,
                                                int nN) {
  int gid = blockIdx.x * 256 + threadIdx.x;
  int node = gid >> 4;
  if (node >= nN) return;
  int c = (gid & 15) << 3;
  const unsigned short* xb = xbf + c;
  int s0 = start[node], s1 = start[node + 1];
  float a0 = 0.f, a1 = 0.f, a2 = 0.f, a3 = 0.f,
        a4 = 0.f, a5 = 0.f, a6 = 0.f, a7 = 0.f;
  int i = s0;
  for (; i + 4 <= s1; i += 4) {
    int sa = srcSorted[i],      sb = srcSorted[i + 1];
    int sc_ = srcSorted[i + 2], sd = srcSorted[i + 3];
    uint4 va = *reinterpret_cast<const uint4*>(xb + (size_t)sa * NCH);
    uint4 vb = *reinterpret_cast<const uint4*>(xb + (size_t)sb * NCH);
    uint4 vc = *reinterpret_cast<const uint4*>(xb + (size_t)sc_ * NCH);
    uint4 vd = *reinterpret_cast<const uint4*>(xb + (size_t)sd * NCH);
    ACC8(va) ACC8(vb) ACC8(vc) ACC8(vd)
  }
  for (; i < s1; i++) {
    int s = srcSorted[i];
    uint4 v = *reinterpret_cast<const uint4*>(xb + (size_t)s * NCH);
    ACC8(v)
  }
  float idg = invdeg[node];
  uint4 o;
  o.x = (unsigned)f2bf_rne(a0 * idg) | ((unsigned)f2bf_rne(a1 * idg) << 16);
  o.y = (unsigned)f2bf_rne(a2 * idg) | ((unsigned)f2bf_rne(a3 * idg) << 16);
  o.z = (unsigned)f2bf_rne(a4 * idg) | ((unsigned)f2bf_rne(a5 * idg) << 16);
  o.w = (unsigned)f2bf_rne(a6 * idg) | ((unsigned)f2bf_rne(a7 * idg) << 16);
  *reinterpret_cast<uint4*>(aggbf + (size_t)node * NCH + c) = o;
}

// ---- MFMA linear: out = [relu]( [agg|x]_bf16 @ (Whi+Wlo) + b ) --------------
__global__ __launch_bounds__(256, 4) void k_linear_mfma(
    const unsigned short* __restrict__ aggbf, const unsigned short* __restrict__ xinbf,
    const unsigned short* __restrict__ Whi, const unsigned short* __restrict__ Wlo,
    const float* __restrict__ bias, float* __restrict__ outF,
    unsigned short* __restrict__ outBf, int relu, int nNodes) {
  int t = threadIdx.x;
  int wave = t >> 6;
  int lane = t & 63;
  int l15 = lane & 15;
  int lq  = lane >> 4;
  int r0 = (blockIdx.x * 4 + wave) * 16;

  const bf16x8* WhiV = reinterpret_cast<const bf16x8*>(Whi) + lane;
  const bf16x8* WloV = reinterpret_cast<const bf16x8*>(Wlo) + lane;

  f32x4 acc[8];
#pragma unroll
  for (int i = 0; i < 8; i++) acc[i] = (f32x4){0.f, 0.f, 0.f, 0.f};

  int arow = r0 + l15;
  if (arow >= nNodes) arow = nNodes - 1;

#pragma unroll
  for (int kc = 0; kc < 8; kc++) {
    const unsigned short* ab = (kc < 4) ? aggbf : xinbf;
    int k128 = (kc & 3) * 32 + lq * 8;
    bf16x8 a = *reinterpret_cast<const bf16x8*>(ab + (size_t)arow * NCH + k128);
#pragma unroll
    for (int nt = 0; nt < 8; nt++) {
      int fidx = (kc * 8 + nt) * 64;
      bf16x8 bhi = WhiV[fidx];
      bf16x8 blo = WloV[fidx];
      acc[nt] = __builtin_amdgcn_mfma_f32_16x16x32_bf16(a, bhi, acc[nt], 0, 0, 0);
      acc[nt] = __builtin_amdgcn_mfma_f32_16x16x32_bf16(a, blo, acc[nt], 0, 0, 0);
    }
  }

#pragma unroll
  for (int nt = 0; nt < 8; nt++) {
    int col = nt * 16 + l15;
    float bv = bias[col];
#pragma unroll
    for (int i = 0; i < 4; i++) {
      int row = r0 + lq * 4 + i;
      if (row < nNodes) {
        float v = acc[nt][i] + bv;
        if (relu) v = fmaxf(v, 0.f);
        if (outBf) outBf[(size_t)row * NCH + col] = f2bf_rne(v);
        else       outF[(size_t)row * NCH + col] = v;
      }
    }
  }
}

extern "C" void kernel_launch(void* const* d_in, const int* in_sizes, int n_in,
                              void* d_out, int out_size, void* d_ws, size_t ws_size,
                              hipStream_t stream) {
  const float* x   = (const float*)d_in[0];
  const int*   ei  = (const int*)d_in[1];
  const float* W1l = (const float*)d_in[2];
  const float* W1r = (const float*)d_in[3];
  const float* b1  = (const float*)d_in[4];
  const float* W2l = (const float*)d_in[5];
  const float* W2r = (const float*)d_in[6];
  const float* b2  = (const float*)d_in[7];
  float* out = (float*)d_out;

  const int nE = in_sizes[1] / 2;     // 800000
  const int nN = in_sizes[0] / NCH;   // 50000
  const int* src = ei;
  const int* dst = ei + nE;
  const int nBkt = (nN + BKT_NODES - 1) >> BKT_SHIFT;   // 391

  size_t bfBytes = (size_t)nN * NCH * sizeof(unsigned short);   // 12.8 MB
  size_t wBytes  = (size_t)128 * 256 * sizeof(unsigned short);  // 64 KB
  auto align256 = [](size_t v) { return (v + 255) & ~(size_t)255; };

  char* ws = (char*)d_ws;
  unsigned short* xbf   = (unsigned short*)ws;  ws += bfBytes;
  unsigned short* aggbf = (unsigned short*)ws;  ws += bfBytes;
  unsigned short* hbf   = (unsigned short*)ws;  ws += bfBytes;
  uint2* binned    = (uint2*)ws;                ws += (size_t)nE * sizeof(uint2);
  int*   srcSorted = (int*)ws;                  ws += align256((size_t)nE * sizeof(int));
  int*   startRow  = (int*)ws;                  ws += align256((size_t)(nN + 1) * sizeof(int));
  float* invdeg    = (float*)ws;                ws += align256((size_t)nN * sizeof(float));
  int*   partial   = (int*)ws;                  ws += (size_t)NHIST * MAXBKT * sizeof(int);
  int*   bktCursor = (int*)ws;                  ws += MAXBKT * sizeof(int);
  int*   bktBase   = (int*)ws;                  ws += align256((MAXBKT + 1) * sizeof(int));
  unsigned short* W1hi = (unsigned short*)ws;   ws += wBytes;
  unsigned short* W1lo = (unsigned short*)ws;   ws += wBytes;
  unsigned short* W2hi = (unsigned short*)ws;   ws += wBytes;
  unsigned short* W2lo = (unsigned short*)ws;   ws += wBytes;

  // ---- CSR build (no memset: partial hist + scan-side cursor zeroing) ----
  k_bkthist<<<NHIST, 256, 0, stream>>>(dst, partial, nE, nBkt);
  k_bktscan<<<1, 512, 0, stream>>>(partial, bktBase, bktCursor, nBkt);
  k_bin<<<(nE + BIN_BATCH - 1) / BIN_BATCH, 256, 0, stream>>>(src, dst, bktBase,
                                                              bktCursor, binned, nE, nBkt);
  k_build<<<nBkt, 256, 0, stream>>>(binned, bktBase, startRow, invdeg, srcSorted, nN, nE);

  // ---- fused feature/weight prep (one dispatch) ----
  {
    int n8 = nN * NCH / 8;                       // 800000, multiple of 256
    int total = n8 + 2 * 32768;
    k_prep<<<(total + 255) / 256, 256, 0, stream>>>(x, xbf, W1l, W1r, W2l, W2r,
                                                    W1hi, W1lo, W2hi, W2lo, n8);
  }

  int gatherBlocks = (nN * 16 + 255) / 256;
  int linBlocks = (nN + 63) / 64;

  // ---- layer 1 ----
  k_gather<<<gatherBlocks, 256, 0, stream>>>(xbf, srcSorted, startRow, invdeg, aggbf, nN);
  k_linear_mfma<<<linBlocks, 256, 0, stream>>>(aggbf, xbf, W1hi, W1lo, b1,
                                               nullptr, hbf, 1, nN);

  // ---- layer 2 ----
  k_gather<<<gatherBlocks, 256, 0, stream>>>(hbf, srcSorted, startRow, invdeg, aggbf, nN);
  k_linear_mfma<<<linBlocks, 256, 0, stream>>>(aggbf, hbf, W2hi, W2lo, b2,
                                               out, nullptr, 0, nN);
}